// Round 6
// baseline (272.582 us; speedup 1.0000x reference)
//
#include <hip/hip_runtime.h>
#include <stdint.h>

// ---- problem constants ----
#define DIM    512
#define DSTATE 16
#define DINNER 1024
#define DTRANK 32
#define BB     2
#define LL     2048
#define NTOK   (BB*LL)      // 4096
#define NCHUNK 64
#define CLEN   (LL/NCHUNK)  // 32
#define NSUB   4
#define SLEN   (CLEN/NSUB)  // 8
#define NP     8            // x_proj K-split partials

typedef __bf16 bf16;
typedef bf16  bf16x8 __attribute__((ext_vector_type(8)));
typedef bf16  bf16x2 __attribute__((ext_vector_type(2)));
typedef float f32x4  __attribute__((ext_vector_type(4)));

// I/O dtype: FP32. Internals: bf16.
// Perf ledger: r11=222.1, r14=219.1, r16(delta fused into scan_a)=197.3 BEST,
// r17(conv->x_proj fusion)=258.4 FAILED (cache eviction + low occ),
// r18(NCHUNK=128)=197.6 NEUTRAL (occ gain offset by 2x S traffic + 2x scan_b),
// r19(cooperative fused scan)=FAILED correctness — grid.sync/coop launch does
//   not work under the harness graph capture. NO cooperative launches here.
// This round: r16 structure + INTRA-BLOCK sub-chunk split for scan_a/scan_c.
// Scans were latency-bound at 8 waves/CU (grid-capped). 1024-thr blocks =
// 256 channels x 4 subs of 8 tokens; LDS combine with P=exp(An*sum_delta_sub)
// (same recombination identity as the chunk level) -> 16 waves/CU, S size and
// scan_b untouched.

static __device__ __forceinline__ bf16x8 cvt8(const float* p)
{
    f32x4 a = *(const f32x4*)p, b = *(const f32x4*)(p + 4);
    bf16x8 o;
#pragma unroll
    for (int i = 0; i < 4; i++) { o[i] = (bf16)a[i]; o[4 + i] = (bf16)b[i]; }
    return o;
}

// async global->LDS, 16B per lane; LDS dest = wave-uniform base + lane*16 [m97]
static __device__ __forceinline__ void gload_lds16(const bf16* g, bf16* l)
{
    __builtin_amdgcn_global_load_lds(
        (const __attribute__((address_space(1))) void*)g,
        (__attribute__((address_space(3))) void*)l, 16, 0, 0);
}

// ---- bf16 weight shadow ----
#define WIN_N  (2*DINNER*DIM)          // 1,048,576
#define WX_N   (64*DINNER)             // 65,536
#define WOUT_N (DIM*DINNER)            // 524,288
#define WCVT_BLOCKS 800                // (WIN_N+WX_N+WOUT_N)/(256*8)
#define LN_BLOCKS   (NTOK/4)           // 1024

// ---------------------------------------------------------------------------
// prep: [0,800) weight cvt | [800,1824) LayerNorm
// ---------------------------------------------------------------------------
__global__ __launch_bounds__(256) void prep_kernel(const float* __restrict__ win,
                                                   const float* __restrict__ wx,
                                                   const float* __restrict__ wout,
                                                   bf16* __restrict__ wb,
                                                   const float* __restrict__ x,
                                                   const float* __restrict__ gamma,
                                                   const float* __restrict__ beta,
                                                   bf16* __restrict__ h)
{
    if (blockIdx.x < WCVT_BLOCKS) {
        int i = (blockIdx.x * 256 + threadIdx.x) * 8;
        const float* s; int j; bf16* dpt;
        if      (i < WIN_N)        { s = win;  j = i;                 dpt = wb; }
        else if (i < WIN_N + WX_N) { s = wx;   j = i - WIN_N;         dpt = wb + WIN_N; }
        else                       { s = wout; j = i - WIN_N - WX_N;  dpt = wb + WIN_N + WX_N; }
        *(bf16x8*)&dpt[j] = cvt8(&s[j]);
        return;
    }
    int bid = blockIdx.x - WCVT_BLOCKS;
    int w = threadIdx.x >> 6, lane = threadIdx.x & 63;
    int token = bid * 4 + w;
    const float* xr = x + (size_t)token * DIM + lane * 8;
    f32x4 va = *(const f32x4*)xr, vb = *(const f32x4*)(xr + 4);
    float vals[8];
#pragma unroll
    for (int i = 0; i < 4; i++) { vals[i] = va[i]; vals[4 + i] = vb[i]; }
    float s = 0.f;
#pragma unroll
    for (int i = 0; i < 8; i++) s += vals[i];
#pragma unroll
    for (int off = 32; off > 0; off >>= 1) s += __shfl_xor(s, off);
    float mean = s * (1.f / DIM);
    float vs = 0.f;
#pragma unroll
    for (int i = 0; i < 8; i++) { float d = vals[i] - mean; vs += d * d; }
#pragma unroll
    for (int off = 32; off > 0; off >>= 1) vs += __shfl_xor(vs, off);
    float rstd = rsqrtf(vs * (1.f / DIM) + 1e-5f);
    f32x4 ga = *(const f32x4*)(gamma + lane * 8), gb = *(const f32x4*)(gamma + lane * 8 + 4);
    f32x4 ba = *(const f32x4*)(beta + lane * 8),  bb = *(const f32x4*)(beta + lane * 8 + 4);
    bf16x8 o;
#pragma unroll
    for (int i = 0; i < 4; i++) {
        o[i]     = (bf16)((vals[i]     - mean) * rstd * ga[i] + ba[i]);
        o[4 + i] = (bf16)((vals[4 + i] - mean) * rstd * gb[i] + bb[i]);
    }
    *(bf16x8*)(h + (size_t)token * DIM + lane * 8) = o;
}

// ---------------------------------------------------------------------------
// Tiled MFMA GEMM, single-buffer 2-barrier global_load_lds staging (r11 proven).
// C[M,N] = A[M,K(lda)] * W[N,K(ldb)]^T.
// EPI: 0 = store bf16, 1 = fp32 partial store Cout[z][M][N], 2 = fp32 resid+store
// ---------------------------------------------------------------------------
template<int BM, int BN, int TM, int TN, int EPI>
__global__ __launch_bounds__(256) void gemm_kernel(const bf16* __restrict__ A, int lda,
                                                   const bf16* __restrict__ Bw, int ldb,
                                                   void* __restrict__ Cout,
                                                   const float* __restrict__ resid,
                                                   int M, int N, int K,
                                                   int kStart, int kLen)
{
    constexpr int WCols = BN / (TN * 16);
    constexpr int WRows = 4 / WCols;
    static_assert(WRows * TM * 16 == BM, "tile mismatch");
    __shared__ __align__(16) bf16 lsA[BM * 32];
    __shared__ __align__(16) bf16 lsB[BN * 32];
    const int tid  = threadIdx.x;
    const int lane = tid & 63;
    const int w    = tid >> 6;
    const int wr = w / WCols, wc = w % WCols;
    const int fr = lane & 15, q = lane >> 4;
    const int m0 = blockIdx.y * BM, n0 = blockIdx.x * BN;
    const int ks = kStart + blockIdx.z * kLen;

    f32x4 acc[TM][TN];
#pragma unroll
    for (int i = 0; i < TM; i++)
#pragma unroll
        for (int j = 0; j < TN; j++) acc[i][j] = (f32x4){0.f, 0.f, 0.f, 0.f};

    constexpr int NCA = (BM * 4) / 256;
    constexpr int NCB = (BN * 4) / 256;

    for (int k0 = ks; k0 < ks + kLen; k0 += 32) {
        __syncthreads();
#pragma unroll
        for (int c = 0; c < NCA; c++) {
            int lin = tid + c * 256;
            gload_lds16(&A[(size_t)(m0 + (lin >> 2)) * lda + k0 + (lin & 3) * 8], &lsA[lin * 8]);
        }
#pragma unroll
        for (int c = 0; c < NCB; c++) {
            int lin = tid + c * 256;
            gload_lds16(&Bw[(size_t)(n0 + (lin >> 2)) * ldb + k0 + (lin & 3) * 8], &lsB[lin * 8]);
        }
        __syncthreads();
        bf16x8 af[TM], bfr[TN];
#pragma unroll
        for (int i = 0; i < TM; i++)
            af[i] = *(const bf16x8*)&lsA[(wr * TM * 16 + i * 16 + fr) * 32 + q * 8];
#pragma unroll
        for (int j = 0; j < TN; j++)
            bfr[j] = *(const bf16x8*)&lsB[(wc * TN * 16 + j * 16 + fr) * 32 + q * 8];
#pragma unroll
        for (int i = 0; i < TM; i++)
#pragma unroll
            for (int j = 0; j < TN; j++)
                acc[i][j] = __builtin_amdgcn_mfma_f32_16x16x32_bf16(af[i], bfr[j], acc[i][j], 0, 0, 0);
    }

    // epilogue: D[m][n] -> col = lane&15, row = (lane>>4)*4 + r  [m89/m91]
#pragma unroll
    for (int i = 0; i < TM; i++) {
#pragma unroll
        for (int j = 0; j < TN; j++) {
#pragma unroll
            for (int r = 0; r < 4; r++) {
                int row = m0 + wr * TM * 16 + i * 16 + q * 4 + r;
                int col = n0 + wc * TN * 16 + j * 16 + fr;
                float v = acc[i][j][r];
                if (EPI == 0) {
                    ((bf16*)Cout)[(size_t)row * N + col] = (bf16)v;
                } else if (EPI == 1) {
                    ((float*)Cout)[((size_t)blockIdx.z * M + row) * N + col] = v;
                } else {
                    size_t idx = (size_t)row * N + col;
                    ((float*)Cout)[idx] = resid[idx] + v;
                }
            }
        }
    }
}

// ---------------------------------------------------------------------------
// Depthwise causal conv (taps=4) + bias + SiLU. 8 channels/thread, bf16x8 I/O.
// ---------------------------------------------------------------------------
__global__ __launch_bounds__(256) void conv_kernel(const bf16* __restrict__ xz,
                                                   const float* __restrict__ cw,
                                                   const float* __restrict__ cb,
                                                   bf16* __restrict__ uact)
{
    int idx = blockIdx.x * 256 + threadIdx.x;   // NTOK * 128
    int c   = (idx & 127) * 8;
    int tok = idx >> 7;
    int b = tok >> 11, l = tok & 2047;
    float a[8];
    {
        f32x4 c0 = *(const f32x4*)&cb[c], c1 = *(const f32x4*)&cb[c + 4];
#pragma unroll
        for (int j = 0; j < 4; j++) { a[j] = c0[j]; a[4 + j] = c1[j]; }
    }
    float wv[8][4];
#pragma unroll
    for (int j = 0; j < 8; j++) {
        f32x4 wq = *(const f32x4*)&cw[(c + j) * 4];
#pragma unroll
        for (int k = 0; k < 4; k++) wv[j][k] = wq[k];
    }
#pragma unroll
    for (int k = 0; k < 4; k++) {
        int ls = l - 3 + k;
        if (ls >= 0) {
            bf16x8 uv = *(const bf16x8*)&xz[((size_t)(b * LL + ls)) * (2 * DINNER) + c];
#pragma unroll
            for (int j = 0; j < 8; j++) a[j] += (float)uv[j] * wv[j][k];
        }
    }
    bf16x8 o;
#pragma unroll
    for (int j = 0; j < 8; j++) {
        float v = a[j] / (1.f + __expf(-a[j]));
        o[j] = (bf16)v;
    }
    *(bf16x8*)&uact[(size_t)tok * DINNER + c] = o;
}

static __device__ __forceinline__ float softplusf(float v)
{
    return (v > 20.f) ? v : __logf(1.f + __expf(v));
}

// ---------------------------------------------------------------------------
// scan_a, sub-chunk split: 1024 thr = 256 channels x NSUB subs of SLEN tokens.
// Each thread scans 8 tokens; LDS combine (P=exp(An*sd_sub)) builds the
// chunk-level S/sumd with identical semantics to the serial 32-token scan.
// ---------------------------------------------------------------------------
__global__ __launch_bounds__(1024) void scan_a(const bf16* __restrict__ uact,
                                               const float* __restrict__ xdblp,
                                               const float* __restrict__ wdt,
                                               const float* __restrict__ bdt,
                                               const float* __restrict__ Alog,
                                               float* __restrict__ S,
                                               float* __restrict__ sumd,
                                               bf16* __restrict__ delta)
{
    const int tid  = threadIdx.x;
    const int sub  = tid >> 8, dloc = tid & 255;
    const int d    = blockIdx.x * 256 + dloc;
    const int chunk = blockIdx.y, b = blockIdx.z;
    const int tok0 = b * LL + chunk * CLEN;
    const int ts0  = tok0 + sub * SLEN;

    __shared__ float sS[CLEN][48];          // x_dbl cols [0,48) NP-summed
    __shared__ float hcomb[NSUB][256][17];  // stride 17: conflict-free
    __shared__ float sdl[NSUB][256];

    if (tid < CLEN * 12) {
        int l = tid / 12, part = tid % 12;
        f32x4 acc = (f32x4){0.f, 0.f, 0.f, 0.f};
#pragma unroll
        for (int p = 0; p < NP; p++)
            acc += *(const f32x4*)&xdblp[((size_t)p * NTOK + tok0 + l) * 64 + part * 4];
        *(f32x4*)&sS[l][part * 4] = acc;
    }

    // dt_proj row (fp32) — live only through the delta dot
    f32x4 wv[8];
#pragma unroll
    for (int i = 0; i < 8; i++) wv[i] = *(const f32x4*)&wdt[(size_t)d * 32 + i * 4];
    float bd = bdt[d];

    bf16 uu[SLEN];
#pragma unroll
    for (int l = 0; l < SLEN; l++)
        uu[l] = uact[(size_t)(ts0 + l) * DINNER + d];

    __syncthreads();

    bf16 dl[SLEN];
#pragma unroll
    for (int l = 0; l < SLEN; l++) {
        float acc = bd;
        const float* row = &sS[sub * SLEN + l][0];
#pragma unroll
        for (int r = 0; r < 8; r++) {
            f32x4 w4 = wv[r];
            acc += row[4 * r + 0] * w4[0] + row[4 * r + 1] * w4[1]
                 + row[4 * r + 2] * w4[2] + row[4 * r + 3] * w4[3];
        }
        bf16 dq = (bf16)softplusf(acc);
        dl[l] = dq;
        delta[(size_t)(ts0 + l) * DINNER + d] = dq;
    }

    float An[16];
#pragma unroll
    for (int n = 0; n < 16; n += 4) {
        f32x4 v = *(const f32x4*)&Alog[(size_t)d * 16 + n];
        An[n] = -__expf(v[0]); An[n + 1] = -__expf(v[1]);
        An[n + 2] = -__expf(v[2]); An[n + 3] = -__expf(v[3]);
    }

    // local sub-scan (zero entry)
    float h[16];
#pragma unroll
    for (int n = 0; n < 16; n++) h[n] = 0.f;
    float sd = 0.f;
#pragma unroll
    for (int l = 0; l < SLEN; l++) {
        float dc = (float)dl[l];
        float du = dc * (float)uu[l];
        sd += dc;
        const float* Brow = &sS[sub * SLEN + l][32];
#pragma unroll
        for (int n = 0; n < 16; n++) {
            float dA = __expf(dc * An[n]);
            h[n] = dA * h[n] + du * Brow[n];
        }
    }
#pragma unroll
    for (int n = 0; n < 16; n++) hcomb[sub][dloc][n] = h[n];
    sdl[sub][dloc] = sd;
    __syncthreads();

    if (sub == NSUB - 1) {
        // combine subs 0..2, then fold own (sub 3) state
        float e[16];
#pragma unroll
        for (int n = 0; n < 16; n++) e[n] = hcomb[0][dloc][n];
        float sdtot = sdl[0][dloc];
#pragma unroll
        for (int t = 1; t < NSUB - 1; t++) {
            float sdt = sdl[t][dloc];
            sdtot += sdt;
#pragma unroll
            for (int n = 0; n < 16; n++)
                e[n] = hcomb[t][dloc][n] + __expf(An[n] * sdt) * e[n];
        }
        sdtot += sd;
        float hc[16];
#pragma unroll
        for (int n = 0; n < 16; n++)
            hc[n] = h[n] + __expf(An[n] * sd) * e[n];

        size_t base = (((size_t)(b * NCHUNK + chunk)) << 14) + (size_t)d * 16;
#pragma unroll
        for (int n = 0; n < 16; n += 4)
            *(f32x4*)&S[base + n] = (f32x4){hc[n], hc[n + 1], hc[n + 2], hc[n + 3]};
        sumd[(b * NCHUNK + chunk) * DINNER + d] = sdtot;
    }
}

// Pass B: serial over chunks; P = exp(An * sumdelta). IN-PLACE entry states.
__global__ __launch_bounds__(256) void scan_b(float* __restrict__ S,
                                              const float* __restrict__ sumd,
                                              const float* __restrict__ Alog)
{
    int idx = blockIdx.x * 256 + threadIdx.x;   // BB * DINNER * DSTATE
    int b = idx >> 14, dn = idx & 16383;
    int d = dn >> 4;
    float An = -__expf(Alog[dn]);               // dn == d*16+n
    float hc = 0.f;
#pragma unroll
    for (int c = 0; c < NCHUNK; c++) {
        size_t o = (((size_t)(b * NCHUNK + c)) << 14) + dn;
        float s_loc = S[o];
        float P = __expf(An * sumd[(b * NCHUNK + c) * DINNER + d]);
        S[o] = hc;
        hc = P * hc + s_loc;
    }
}

// ---------------------------------------------------------------------------
// scan_c, sub-chunk split. Pass 1: local h + sd per sub; combine gives each
// sub its entry state (chunk entry Hent folded through previous subs);
// pass 2: rescan emitting y = C.h + u*D, gated silu(z).
// ---------------------------------------------------------------------------
__global__ __launch_bounds__(1024) void scan_c(const bf16* __restrict__ delta,
                                               const bf16* __restrict__ uact,
                                               const float* __restrict__ xdblp,
                                               const float* __restrict__ Alog,
                                               const float* __restrict__ Hent,
                                               bf16* xz,
                                               const float* __restrict__ Dvec)
{
    const int tid  = threadIdx.x;
    const int sub  = tid >> 8, dloc = tid & 255;
    const int d    = blockIdx.x * 256 + dloc;
    const int chunk = blockIdx.y, b = blockIdx.z;
    const int tok0 = b * LL + chunk * CLEN;
    const int ts0  = tok0 + sub * SLEN;

    __shared__ float sBC[CLEN][32];         // x_dbl cols [32,64) NP-summed
    __shared__ float hcomb[NSUB][256][17];
    __shared__ float sdl[NSUB][256];

    if (tid < CLEN * 8) {
        int l = tid >> 3, part = tid & 7;
        f32x4 acc = (f32x4){0.f, 0.f, 0.f, 0.f};
#pragma unroll
        for (int p = 0; p < NP; p++)
            acc += *(const f32x4*)&xdblp[((size_t)p * NTOK + tok0 + l) * 64 + 32 + part * 4];
        *(f32x4*)&sBC[l][part * 4] = acc;
    }

    float An[16];
#pragma unroll
    for (int n = 0; n < 16; n += 4) {
        f32x4 v = *(const f32x4*)&Alog[(size_t)d * 16 + n];
        An[n] = -__expf(v[0]); An[n + 1] = -__expf(v[1]);
        An[n + 2] = -__expf(v[2]); An[n + 3] = -__expf(v[3]);
    }
    bf16 dl[SLEN], uu[SLEN], zz[SLEN];
#pragma unroll
    for (int l = 0; l < SLEN; l++) {
        dl[l] = delta[(size_t)(ts0 + l) * DINNER + d];
        uu[l] = uact [(size_t)(ts0 + l) * DINNER + d];
        zz[l] = xz[(size_t)(ts0 + l) * (2 * DINNER) + DINNER + d];
    }
    float Dv = Dvec[d];
    float He[16];
    {
        size_t hbase = (((size_t)(b * NCHUNK + chunk)) << 14) + (size_t)d * 16;
#pragma unroll
        for (int n = 0; n < 16; n += 4) {
            f32x4 t = *(const f32x4*)&Hent[hbase + n];
            He[n] = t[0]; He[n + 1] = t[1]; He[n + 2] = t[2]; He[n + 3] = t[3];
        }
    }
    __syncthreads();

    // pass 1: local h (zero entry) + sd
    {
        float h[16];
#pragma unroll
        for (int n = 0; n < 16; n++) h[n] = 0.f;
        float sd = 0.f;
#pragma unroll
        for (int l = 0; l < SLEN; l++) {
            float dc = (float)dl[l];
            float du = dc * (float)uu[l];
            sd += dc;
            const float* Brow = &sBC[sub * SLEN + l][0];
#pragma unroll
            for (int n = 0; n < 16; n++) {
                float dA = __expf(dc * An[n]);
                h[n] = dA * h[n] + du * Brow[n];
            }
        }
#pragma unroll
        for (int n = 0; n < 16; n++) hcomb[sub][dloc][n] = h[n];
        sdl[sub][dloc] = sd;
    }
    __syncthreads();

    // entry for this sub: fold Hent through previous subs (wave-uniform loop)
    float e[16];
#pragma unroll
    for (int n = 0; n < 16; n++) e[n] = He[n];
    for (int t = 0; t < sub; t++) {
        float sdt = sdl[t][dloc];
#pragma unroll
        for (int n = 0; n < 16; n++)
            e[n] = hcomb[t][dloc][n] + __expf(An[n] * sdt) * e[n];
    }

    // pass 2: rescan emitting y
#pragma unroll
    for (int l = 0; l < SLEN; l++) {
        float dc = (float)dl[l];
        float u  = (float)uu[l];
        float z  = (float)zz[l];
        float du = dc * u;
        float y = 0.f;
        const float* row = &sBC[sub * SLEN + l][0];
#pragma unroll
        for (int n = 0; n < 16; n++) {
            float dA = __expf(dc * An[n]);
            e[n] = dA * e[n] + du * row[n];
            y += e[n] * row[16 + n];
        }
        float sz = z / (1.f + __expf(-z));
        xz[(size_t)(ts0 + l) * (2 * DINNER) + d] = (bf16)((y + u * Dv) * sz);
    }
}

// ---------------------------------------------------------------------------
extern "C" void kernel_launch(void* const* d_in, const int* in_sizes, int n_in,
                              void* d_out, int out_size, void* d_ws, size_t ws_size,
                              hipStream_t stream)
{
    const int sh = (n_in >= 13) ? 0 : -1;   // tolerate dropped bool mask
    const float* x     = (const float*)d_in[0];
    const float* gamma = (const float*)d_in[2 + sh];
    const float* beta  = (const float*)d_in[3 + sh];
    const float* win   = (const float*)d_in[4 + sh];
    const float* cw    = (const float*)d_in[5 + sh];
    const float* cb    = (const float*)d_in[6 + sh];
    const float* wx    = (const float*)d_in[7 + sh];
    const float* wdt   = (const float*)d_in[8 + sh];
    const float* bdt   = (const float*)d_in[9 + sh];
    const float* alog  = (const float*)d_in[10 + sh];
    const float* Dv    = (const float*)d_in[11 + sh];
    const float* wout  = (const float*)d_in[12 + sh];

    char* ws = (char*)d_ws;
    // Memory map (~51.2 MB of 256 MiB ws):
    //   [0,4)MB    : h (LN out) -> [0,8)MB delta after gemm_in (h dead)
    //   [8,24)MB   : xz ; yg written in-place into u-columns by scan_c
    //   [24,32)MB  : uact
    //   [32,40)MB  : xdblp fp32 partials [NP][NTOK][64]
    //   [40,48)MB  : S (entry states in-place after scan_b)
    //   [48,51.2)MB: bf16 weight shadow (win | wx | wout)
    //   sumdelta (512 KB fp32) lives in d_out (dead before out_proj).
    bf16*  h     = (bf16*)(ws);
    bf16*  delta = (bf16*)(ws);
    bf16*  xz    = (bf16*)(ws + (8u  << 20));
    bf16*  uact  = (bf16*)(ws + (24u << 20));
    float* xdblp = (float*)(ws + (32u << 20));
    float* S     = (float*)(ws + (40u << 20));
    bf16*  wb    = (bf16*)(ws + (48u << 20));
    float* sumd  = (float*)d_out;

    const bf16* win_b  = wb;
    const bf16* wx_b   = wb + WIN_N;
    const bf16* wout_b = wb + WIN_N + WX_N;

    // 1. weight cvt + LayerNorm
    prep_kernel<<<WCVT_BLOCKS + LN_BLOCKS, 256, 0, stream>>>(
        win, wx, wout, wb, x, gamma, beta, h);

    // 2. in_proj: [4096,512] x [2048,512]^T -> xz [4096,2048] bf16
    gemm_kernel<128, 128, 4, 4, 0><<<dim3(16, 32, 1), 256, 0, stream>>>(
        h, DIM, win_b, DIM, xz, nullptr, NTOK, 2 * DINNER, DIM, 0, DIM);

    // 3. conv + SiLU (2048 blocks, bf16x8)
    conv_kernel<<<(NTOK * (DINNER / 8)) / 256, 256, 0, stream>>>(xz, cw, cb, uact);

    // 4. x_proj: K-split 8, direct fp32 partial stores (512 blocks)
    gemm_kernel<64, 64, 2, 2, 1><<<dim3(1, 64, NP), 256, 0, stream>>>(
        uact, DINNER, wx_b, DINNER, xdblp, nullptr, NTOK, 64, DINNER, 0, DINNER / NP);

    // 5-7. chunked scan (sub-split 1024-thr scan_a/scan_c; scan_b unchanged)
    scan_a<<<dim3(4, NCHUNK, BB), 1024, 0, stream>>>(uact, xdblp, wdt, bdt, alog, S, sumd, delta);
    scan_b<<<(BB * DINNER * DSTATE) / 256, 256, 0, stream>>>(S, sumd, alog);
    scan_c<<<dim3(4, NCHUNK, BB), 1024, 0, stream>>>(delta, uact, xdblp, alog, S, xz, Dv);

    // 8. out_proj + residual -> d_out fp32 (512 blocks, 2/CU)
    gemm_kernel<64, 64, 2, 2, 2><<<dim3(8, 64, 1), 256, 0, stream>>>(
        xz, 2 * DINNER, wout_b, DINNER, d_out, x, NTOK, DIM, DINNER, 0, DINNER);
}

// Round 7
// 268.475 us; speedup vs baseline: 1.0153x; 1.0153x over previous
//
#include <hip/hip_runtime.h>
#include <stdint.h>

// ---- problem constants ----
#define DIM    512
#define DSTATE 16
#define DINNER 1024
#define DTRANK 32
#define BB     2
#define LL     2048
#define NTOK   (BB*LL)      // 4096
#define NCHUNK 64
#define CLEN   (LL/NCHUNK)  // 32
#define NSUB   4
#define SLEN   (CLEN/NSUB)  // 8
#define NP     8            // x_proj K-split partials

typedef __bf16 bf16;
typedef bf16  bf16x8 __attribute__((ext_vector_type(8)));
typedef bf16  bf16x2 __attribute__((ext_vector_type(2)));
typedef float f32x4  __attribute__((ext_vector_type(4)));

// I/O dtype: FP32. Internals: bf16.
// Perf ledger: r11=222.1, r14=219.1, r16(delta fused into scan_a)=197.3 BEST,
// r17(conv->x_proj)=258.4 FAILED (cache eviction), r18(NCHUNK=128)=197.6
// NEUTRAL, r19(cooperative)=WRONG (no coop launch under graph capture),
// r20(sub-split @1024thr)=272.6 FAILED: __launch_bounds__(1024) capped
// VGPR=64 -> scan state spilled to scratch (FETCH 138MB/WRITE 245MB of
// spill traffic per dispatch). Structure was CORRECT (absmax 0.0156).
// This round: same structure + __launch_bounds__(1024,4) -> 1 block/CU,
// VGPR cap 128, no spill; scan_c reloads Hent after pass 1 instead of
// holding He[16] live (peak-pressure tweak). 16 waves/CU vs r16's 8.

static __device__ __forceinline__ bf16x8 cvt8(const float* p)
{
    f32x4 a = *(const f32x4*)p, b = *(const f32x4*)(p + 4);
    bf16x8 o;
#pragma unroll
    for (int i = 0; i < 4; i++) { o[i] = (bf16)a[i]; o[4 + i] = (bf16)b[i]; }
    return o;
}

// async global->LDS, 16B per lane; LDS dest = wave-uniform base + lane*16 [m97]
static __device__ __forceinline__ void gload_lds16(const bf16* g, bf16* l)
{
    __builtin_amdgcn_global_load_lds(
        (const __attribute__((address_space(1))) void*)g,
        (__attribute__((address_space(3))) void*)l, 16, 0, 0);
}

// ---- bf16 weight shadow ----
#define WIN_N  (2*DINNER*DIM)          // 1,048,576
#define WX_N   (64*DINNER)             // 65,536
#define WOUT_N (DIM*DINNER)            // 524,288
#define WCVT_BLOCKS 800                // (WIN_N+WX_N+WOUT_N)/(256*8)
#define LN_BLOCKS   (NTOK/4)           // 1024

// ---------------------------------------------------------------------------
// prep: [0,800) weight cvt | [800,1824) LayerNorm
// ---------------------------------------------------------------------------
__global__ __launch_bounds__(256) void prep_kernel(const float* __restrict__ win,
                                                   const float* __restrict__ wx,
                                                   const float* __restrict__ wout,
                                                   bf16* __restrict__ wb,
                                                   const float* __restrict__ x,
                                                   const float* __restrict__ gamma,
                                                   const float* __restrict__ beta,
                                                   bf16* __restrict__ h)
{
    if (blockIdx.x < WCVT_BLOCKS) {
        int i = (blockIdx.x * 256 + threadIdx.x) * 8;
        const float* s; int j; bf16* dpt;
        if      (i < WIN_N)        { s = win;  j = i;                 dpt = wb; }
        else if (i < WIN_N + WX_N) { s = wx;   j = i - WIN_N;         dpt = wb + WIN_N; }
        else                       { s = wout; j = i - WIN_N - WX_N;  dpt = wb + WIN_N + WX_N; }
        *(bf16x8*)&dpt[j] = cvt8(&s[j]);
        return;
    }
    int bid = blockIdx.x - WCVT_BLOCKS;
    int w = threadIdx.x >> 6, lane = threadIdx.x & 63;
    int token = bid * 4 + w;
    const float* xr = x + (size_t)token * DIM + lane * 8;
    f32x4 va = *(const f32x4*)xr, vb = *(const f32x4*)(xr + 4);
    float vals[8];
#pragma unroll
    for (int i = 0; i < 4; i++) { vals[i] = va[i]; vals[4 + i] = vb[i]; }
    float s = 0.f;
#pragma unroll
    for (int i = 0; i < 8; i++) s += vals[i];
#pragma unroll
    for (int off = 32; off > 0; off >>= 1) s += __shfl_xor(s, off);
    float mean = s * (1.f / DIM);
    float vs = 0.f;
#pragma unroll
    for (int i = 0; i < 8; i++) { float d = vals[i] - mean; vs += d * d; }
#pragma unroll
    for (int off = 32; off > 0; off >>= 1) vs += __shfl_xor(vs, off);
    float rstd = rsqrtf(vs * (1.f / DIM) + 1e-5f);
    f32x4 ga = *(const f32x4*)(gamma + lane * 8), gb = *(const f32x4*)(gamma + lane * 8 + 4);
    f32x4 ba = *(const f32x4*)(beta + lane * 8),  bb = *(const f32x4*)(beta + lane * 8 + 4);
    bf16x8 o;
#pragma unroll
    for (int i = 0; i < 4; i++) {
        o[i]     = (bf16)((vals[i]     - mean) * rstd * ga[i] + ba[i]);
        o[4 + i] = (bf16)((vals[4 + i] - mean) * rstd * gb[i] + bb[i]);
    }
    *(bf16x8*)(h + (size_t)token * DIM + lane * 8) = o;
}

// ---------------------------------------------------------------------------
// Tiled MFMA GEMM, single-buffer 2-barrier global_load_lds staging (r11 proven).
// C[M,N] = A[M,K(lda)] * W[N,K(ldb)]^T.
// EPI: 0 = store bf16, 1 = fp32 partial store Cout[z][M][N], 2 = fp32 resid+store
// ---------------------------------------------------------------------------
template<int BM, int BN, int TM, int TN, int EPI>
__global__ __launch_bounds__(256) void gemm_kernel(const bf16* __restrict__ A, int lda,
                                                   const bf16* __restrict__ Bw, int ldb,
                                                   void* __restrict__ Cout,
                                                   const float* __restrict__ resid,
                                                   int M, int N, int K,
                                                   int kStart, int kLen)
{
    constexpr int WCols = BN / (TN * 16);
    constexpr int WRows = 4 / WCols;
    static_assert(WRows * TM * 16 == BM, "tile mismatch");
    __shared__ __align__(16) bf16 lsA[BM * 32];
    __shared__ __align__(16) bf16 lsB[BN * 32];
    const int tid  = threadIdx.x;
    const int lane = tid & 63;
    const int w    = tid >> 6;
    const int wr = w / WCols, wc = w % WCols;
    const int fr = lane & 15, q = lane >> 4;
    const int m0 = blockIdx.y * BM, n0 = blockIdx.x * BN;
    const int ks = kStart + blockIdx.z * kLen;

    f32x4 acc[TM][TN];
#pragma unroll
    for (int i = 0; i < TM; i++)
#pragma unroll
        for (int j = 0; j < TN; j++) acc[i][j] = (f32x4){0.f, 0.f, 0.f, 0.f};

    constexpr int NCA = (BM * 4) / 256;
    constexpr int NCB = (BN * 4) / 256;

    for (int k0 = ks; k0 < ks + kLen; k0 += 32) {
        __syncthreads();
#pragma unroll
        for (int c = 0; c < NCA; c++) {
            int lin = tid + c * 256;
            gload_lds16(&A[(size_t)(m0 + (lin >> 2)) * lda + k0 + (lin & 3) * 8], &lsA[lin * 8]);
        }
#pragma unroll
        for (int c = 0; c < NCB; c++) {
            int lin = tid + c * 256;
            gload_lds16(&Bw[(size_t)(n0 + (lin >> 2)) * ldb + k0 + (lin & 3) * 8], &lsB[lin * 8]);
        }
        __syncthreads();
        bf16x8 af[TM], bfr[TN];
#pragma unroll
        for (int i = 0; i < TM; i++)
            af[i] = *(const bf16x8*)&lsA[(wr * TM * 16 + i * 16 + fr) * 32 + q * 8];
#pragma unroll
        for (int j = 0; j < TN; j++)
            bfr[j] = *(const bf16x8*)&lsB[(wc * TN * 16 + j * 16 + fr) * 32 + q * 8];
#pragma unroll
        for (int i = 0; i < TM; i++)
#pragma unroll
            for (int j = 0; j < TN; j++)
                acc[i][j] = __builtin_amdgcn_mfma_f32_16x16x32_bf16(af[i], bfr[j], acc[i][j], 0, 0, 0);
    }

    // epilogue: D[m][n] -> col = lane&15, row = (lane>>4)*4 + r  [m89/m91]
#pragma unroll
    for (int i = 0; i < TM; i++) {
#pragma unroll
        for (int j = 0; j < TN; j++) {
#pragma unroll
            for (int r = 0; r < 4; r++) {
                int row = m0 + wr * TM * 16 + i * 16 + q * 4 + r;
                int col = n0 + wc * TN * 16 + j * 16 + fr;
                float v = acc[i][j][r];
                if (EPI == 0) {
                    ((bf16*)Cout)[(size_t)row * N + col] = (bf16)v;
                } else if (EPI == 1) {
                    ((float*)Cout)[((size_t)blockIdx.z * M + row) * N + col] = v;
                } else {
                    size_t idx = (size_t)row * N + col;
                    ((float*)Cout)[idx] = resid[idx] + v;
                }
            }
        }
    }
}

// ---------------------------------------------------------------------------
// Depthwise causal conv (taps=4) + bias + SiLU. 8 channels/thread, bf16x8 I/O.
// ---------------------------------------------------------------------------
__global__ __launch_bounds__(256) void conv_kernel(const bf16* __restrict__ xz,
                                                   const float* __restrict__ cw,
                                                   const float* __restrict__ cb,
                                                   bf16* __restrict__ uact)
{
    int idx = blockIdx.x * 256 + threadIdx.x;   // NTOK * 128
    int c   = (idx & 127) * 8;
    int tok = idx >> 7;
    int b = tok >> 11, l = tok & 2047;
    float a[8];
    {
        f32x4 c0 = *(const f32x4*)&cb[c], c1 = *(const f32x4*)&cb[c + 4];
#pragma unroll
        for (int j = 0; j < 4; j++) { a[j] = c0[j]; a[4 + j] = c1[j]; }
    }
    float wv[8][4];
#pragma unroll
    for (int j = 0; j < 8; j++) {
        f32x4 wq = *(const f32x4*)&cw[(c + j) * 4];
#pragma unroll
        for (int k = 0; k < 4; k++) wv[j][k] = wq[k];
    }
#pragma unroll
    for (int k = 0; k < 4; k++) {
        int ls = l - 3 + k;
        if (ls >= 0) {
            bf16x8 uv = *(const bf16x8*)&xz[((size_t)(b * LL + ls)) * (2 * DINNER) + c];
#pragma unroll
            for (int j = 0; j < 8; j++) a[j] += (float)uv[j] * wv[j][k];
        }
    }
    bf16x8 o;
#pragma unroll
    for (int j = 0; j < 8; j++) {
        float v = a[j] / (1.f + __expf(-a[j]));
        o[j] = (bf16)v;
    }
    *(bf16x8*)&uact[(size_t)tok * DINNER + c] = o;
}

static __device__ __forceinline__ float softplusf(float v)
{
    return (v > 20.f) ? v : __logf(1.f + __expf(v));
}

// ---------------------------------------------------------------------------
// scan_a, sub-chunk split: 1024 thr = 256 channels x NSUB subs of SLEN tokens.
// __launch_bounds__(1024,4): 1 block/CU, VGPR cap 128 (r20's 64-cap spilled).
// ---------------------------------------------------------------------------
__global__ __launch_bounds__(1024, 4) void scan_a(const bf16* __restrict__ uact,
                                                  const float* __restrict__ xdblp,
                                                  const float* __restrict__ wdt,
                                                  const float* __restrict__ bdt,
                                                  const float* __restrict__ Alog,
                                                  float* __restrict__ S,
                                                  float* __restrict__ sumd,
                                                  bf16* __restrict__ delta)
{
    const int tid  = threadIdx.x;
    const int sub  = tid >> 8, dloc = tid & 255;
    const int d    = blockIdx.x * 256 + dloc;
    const int chunk = blockIdx.y, b = blockIdx.z;
    const int tok0 = b * LL + chunk * CLEN;
    const int ts0  = tok0 + sub * SLEN;

    __shared__ float sS[CLEN][48];          // x_dbl cols [0,48) NP-summed
    __shared__ float hcomb[NSUB][256][17];  // stride 17: conflict-free
    __shared__ float sdl[NSUB][256];

    if (tid < CLEN * 12) {
        int l = tid / 12, part = tid % 12;
        f32x4 acc = (f32x4){0.f, 0.f, 0.f, 0.f};
#pragma unroll
        for (int p = 0; p < NP; p++)
            acc += *(const f32x4*)&xdblp[((size_t)p * NTOK + tok0 + l) * 64 + part * 4];
        *(f32x4*)&sS[l][part * 4] = acc;
    }

    // dt_proj row (fp32) — live only through the delta dot
    f32x4 wv[8];
#pragma unroll
    for (int i = 0; i < 8; i++) wv[i] = *(const f32x4*)&wdt[(size_t)d * 32 + i * 4];
    float bd = bdt[d];

    bf16 uu[SLEN];
#pragma unroll
    for (int l = 0; l < SLEN; l++)
        uu[l] = uact[(size_t)(ts0 + l) * DINNER + d];

    __syncthreads();

    bf16 dl[SLEN];
#pragma unroll
    for (int l = 0; l < SLEN; l++) {
        float acc = bd;
        const float* row = &sS[sub * SLEN + l][0];
#pragma unroll
        for (int r = 0; r < 8; r++) {
            f32x4 w4 = wv[r];
            acc += row[4 * r + 0] * w4[0] + row[4 * r + 1] * w4[1]
                 + row[4 * r + 2] * w4[2] + row[4 * r + 3] * w4[3];
        }
        bf16 dq = (bf16)softplusf(acc);
        dl[l] = dq;
        delta[(size_t)(ts0 + l) * DINNER + d] = dq;
    }

    float An[16];
#pragma unroll
    for (int n = 0; n < 16; n += 4) {
        f32x4 v = *(const f32x4*)&Alog[(size_t)d * 16 + n];
        An[n] = -__expf(v[0]); An[n + 1] = -__expf(v[1]);
        An[n + 2] = -__expf(v[2]); An[n + 3] = -__expf(v[3]);
    }

    // local sub-scan (zero entry)
    float h[16];
#pragma unroll
    for (int n = 0; n < 16; n++) h[n] = 0.f;
    float sd = 0.f;
#pragma unroll
    for (int l = 0; l < SLEN; l++) {
        float dc = (float)dl[l];
        float du = dc * (float)uu[l];
        sd += dc;
        const float* Brow = &sS[sub * SLEN + l][32];
#pragma unroll
        for (int n = 0; n < 16; n++) {
            float dA = __expf(dc * An[n]);
            h[n] = dA * h[n] + du * Brow[n];
        }
    }
#pragma unroll
    for (int n = 0; n < 16; n++) hcomb[sub][dloc][n] = h[n];
    sdl[sub][dloc] = sd;
    __syncthreads();

    if (sub == NSUB - 1) {
        // combine subs 0..2, then fold own (sub 3) state
        float e[16];
#pragma unroll
        for (int n = 0; n < 16; n++) e[n] = hcomb[0][dloc][n];
        float sdtot = sdl[0][dloc];
#pragma unroll
        for (int t = 1; t < NSUB - 1; t++) {
            float sdt = sdl[t][dloc];
            sdtot += sdt;
#pragma unroll
            for (int n = 0; n < 16; n++)
                e[n] = hcomb[t][dloc][n] + __expf(An[n] * sdt) * e[n];
        }
        sdtot += sd;
        float hc[16];
#pragma unroll
        for (int n = 0; n < 16; n++)
            hc[n] = h[n] + __expf(An[n] * sd) * e[n];

        size_t base = (((size_t)(b * NCHUNK + chunk)) << 14) + (size_t)d * 16;
#pragma unroll
        for (int n = 0; n < 16; n += 4)
            *(f32x4*)&S[base + n] = (f32x4){hc[n], hc[n + 1], hc[n + 2], hc[n + 3]};
        sumd[(b * NCHUNK + chunk) * DINNER + d] = sdtot;
    }
}

// Pass B: serial over chunks; P = exp(An * sumdelta). IN-PLACE entry states.
__global__ __launch_bounds__(256) void scan_b(float* __restrict__ S,
                                              const float* __restrict__ sumd,
                                              const float* __restrict__ Alog)
{
    int idx = blockIdx.x * 256 + threadIdx.x;   // BB * DINNER * DSTATE
    int b = idx >> 14, dn = idx & 16383;
    int d = dn >> 4;
    float An = -__expf(Alog[dn]);               // dn == d*16+n
    float hc = 0.f;
#pragma unroll
    for (int c = 0; c < NCHUNK; c++) {
        size_t o = (((size_t)(b * NCHUNK + c)) << 14) + dn;
        float s_loc = S[o];
        float P = __expf(An * sumd[(b * NCHUNK + c) * DINNER + d]);
        S[o] = hc;
        hc = P * hc + s_loc;
    }
}

// ---------------------------------------------------------------------------
// scan_c, sub-chunk split. Pass 1: local h + sd per sub; combine gives each
// sub its entry state (chunk entry Hent folded through previous subs, Hent
// reloaded AFTER pass 1 to cut peak VGPR pressure); pass 2: rescan emitting y.
// ---------------------------------------------------------------------------
__global__ __launch_bounds__(1024, 4) void scan_c(const bf16* __restrict__ delta,
                                                  const bf16* __restrict__ uact,
                                                  const float* __restrict__ xdblp,
                                                  const float* __restrict__ Alog,
                                                  const float* __restrict__ Hent,
                                                  bf16* xz,
                                                  const float* __restrict__ Dvec)
{
    const int tid  = threadIdx.x;
    const int sub  = tid >> 8, dloc = tid & 255;
    const int d    = blockIdx.x * 256 + dloc;
    const int chunk = blockIdx.y, b = blockIdx.z;
    const int tok0 = b * LL + chunk * CLEN;
    const int ts0  = tok0 + sub * SLEN;

    __shared__ float sBC[CLEN][32];         // x_dbl cols [32,64) NP-summed
    __shared__ float hcomb[NSUB][256][17];
    __shared__ float sdl[NSUB][256];

    if (tid < CLEN * 8) {
        int l = tid >> 3, part = tid & 7;
        f32x4 acc = (f32x4){0.f, 0.f, 0.f, 0.f};
#pragma unroll
        for (int p = 0; p < NP; p++)
            acc += *(const f32x4*)&xdblp[((size_t)p * NTOK + tok0 + l) * 64 + 32 + part * 4];
        *(f32x4*)&sBC[l][part * 4] = acc;
    }

    float An[16];
#pragma unroll
    for (int n = 0; n < 16; n += 4) {
        f32x4 v = *(const f32x4*)&Alog[(size_t)d * 16 + n];
        An[n] = -__expf(v[0]); An[n + 1] = -__expf(v[1]);
        An[n + 2] = -__expf(v[2]); An[n + 3] = -__expf(v[3]);
    }
    bf16 dl[SLEN], uu[SLEN], zz[SLEN];
#pragma unroll
    for (int l = 0; l < SLEN; l++) {
        dl[l] = delta[(size_t)(ts0 + l) * DINNER + d];
        uu[l] = uact [(size_t)(ts0 + l) * DINNER + d];
        zz[l] = xz[(size_t)(ts0 + l) * (2 * DINNER) + DINNER + d];
    }
    float Dv = Dvec[d];
    __syncthreads();

    // pass 1: local h (zero entry) + sd
    {
        float h[16];
#pragma unroll
        for (int n = 0; n < 16; n++) h[n] = 0.f;
        float sd = 0.f;
#pragma unroll
        for (int l = 0; l < SLEN; l++) {
            float dc = (float)dl[l];
            float du = dc * (float)uu[l];
            sd += dc;
            const float* Brow = &sBC[sub * SLEN + l][0];
#pragma unroll
            for (int n = 0; n < 16; n++) {
                float dA = __expf(dc * An[n]);
                h[n] = dA * h[n] + du * Brow[n];
            }
        }
#pragma unroll
        for (int n = 0; n < 16; n++) hcomb[sub][dloc][n] = h[n];
        sdl[sub][dloc] = sd;
    }
    __syncthreads();

    // entry for this sub: fold Hent (reloaded here, L2-hot) through prev subs
    float e[16];
    {
        size_t hbase = (((size_t)(b * NCHUNK + chunk)) << 14) + (size_t)d * 16;
#pragma unroll
        for (int n = 0; n < 16; n += 4) {
            f32x4 t = *(const f32x4*)&Hent[hbase + n];
            e[n] = t[0]; e[n + 1] = t[1]; e[n + 2] = t[2]; e[n + 3] = t[3];
        }
    }
    for (int t = 0; t < sub; t++) {
        float sdt = sdl[t][dloc];
#pragma unroll
        for (int n = 0; n < 16; n++)
            e[n] = hcomb[t][dloc][n] + __expf(An[n] * sdt) * e[n];
    }

    // pass 2: rescan emitting y
#pragma unroll
    for (int l = 0; l < SLEN; l++) {
        float dc = (float)dl[l];
        float u  = (float)uu[l];
        float z  = (float)zz[l];
        float du = dc * u;
        float y = 0.f;
        const float* row = &sBC[sub * SLEN + l][0];
#pragma unroll
        for (int n = 0; n < 16; n++) {
            float dA = __expf(dc * An[n]);
            e[n] = dA * e[n] + du * row[n];
            y += e[n] * row[16 + n];
        }
        float sz = z / (1.f + __expf(-z));
        xz[(size_t)(ts0 + l) * (2 * DINNER) + d] = (bf16)((y + u * Dv) * sz);
    }
}

// ---------------------------------------------------------------------------
extern "C" void kernel_launch(void* const* d_in, const int* in_sizes, int n_in,
                              void* d_out, int out_size, void* d_ws, size_t ws_size,
                              hipStream_t stream)
{
    const int sh = (n_in >= 13) ? 0 : -1;   // tolerate dropped bool mask
    const float* x     = (const float*)d_in[0];
    const float* gamma = (const float*)d_in[2 + sh];
    const float* beta  = (const float*)d_in[3 + sh];
    const float* win   = (const float*)d_in[4 + sh];
    const float* cw    = (const float*)d_in[5 + sh];
    const float* cb    = (const float*)d_in[6 + sh];
    const float* wx    = (const float*)d_in[7 + sh];
    const float* wdt   = (const float*)d_in[8 + sh];
    const float* bdt   = (const float*)d_in[9 + sh];
    const float* alog  = (const float*)d_in[10 + sh];
    const float* Dv    = (const float*)d_in[11 + sh];
    const float* wout  = (const float*)d_in[12 + sh];

    char* ws = (char*)d_ws;
    // Memory map (~51.2 MB of 256 MiB ws):
    //   [0,4)MB    : h (LN out) -> [0,8)MB delta after gemm_in (h dead)
    //   [8,24)MB   : xz ; yg written in-place into u-columns by scan_c
    //   [24,32)MB  : uact
    //   [32,40)MB  : xdblp fp32 partials [NP][NTOK][64]
    //   [40,48)MB  : S (entry states in-place after scan_b)
    //   [48,51.2)MB: bf16 weight shadow (win | wx | wout)
    //   sumdelta (512 KB fp32) lives in d_out (dead before out_proj).
    bf16*  h     = (bf16*)(ws);
    bf16*  delta = (bf16*)(ws);
    bf16*  xz    = (bf16*)(ws + (8u  << 20));
    bf16*  uact  = (bf16*)(ws + (24u << 20));
    float* xdblp = (float*)(ws + (32u << 20));
    float* S     = (float*)(ws + (40u << 20));
    bf16*  wb    = (bf16*)(ws + (48u << 20));
    float* sumd  = (float*)d_out;

    const bf16* win_b  = wb;
    const bf16* wx_b   = wb + WIN_N;
    const bf16* wout_b = wb + WIN_N + WX_N;

    // 1. weight cvt + LayerNorm
    prep_kernel<<<WCVT_BLOCKS + LN_BLOCKS, 256, 0, stream>>>(
        win, wx, wout, wb, x, gamma, beta, h);

    // 2. in_proj: [4096,512] x [2048,512]^T -> xz [4096,2048] bf16
    gemm_kernel<128, 128, 4, 4, 0><<<dim3(16, 32, 1), 256, 0, stream>>>(
        h, DIM, win_b, DIM, xz, nullptr, NTOK, 2 * DINNER, DIM, 0, DIM);

    // 3. conv + SiLU (2048 blocks, bf16x8)
    conv_kernel<<<(NTOK * (DINNER / 8)) / 256, 256, 0, stream>>>(xz, cw, cb, uact);

    // 4. x_proj: K-split 8, direct fp32 partial stores (512 blocks)
    gemm_kernel<64, 64, 2, 2, 1><<<dim3(1, 64, NP), 256, 0, stream>>>(
        uact, DINNER, wx_b, DINNER, xdblp, nullptr, NTOK, 64, DINNER, 0, DINNER / NP);

    // 5-7. chunked scan (sub-split 1024-thr scan_a/scan_c @ VGPR128; scan_b same)
    scan_a<<<dim3(4, NCHUNK, BB), 1024, 0, stream>>>(uact, xdblp, wdt, bdt, alog, S, sumd, delta);
    scan_b<<<(BB * DINNER * DSTATE) / 256, 256, 0, stream>>>(S, sumd, alog);
    scan_c<<<dim3(4, NCHUNK, BB), 1024, 0, stream>>>(delta, uact, xdblp, alog, S, xz, Dv);

    // 8. out_proj + residual -> d_out fp32 (512 blocks, 2/CU)
    gemm_kernel<64, 64, 2, 2, 2><<<dim3(8, 64, 1), 256, 0, stream>>>(
        xz, 2 * DINNER, wout_b, DINNER, d_out, x, NTOK, DIM, DINNER, 0, DINNER);
}

// Round 8
// 204.024 us; speedup vs baseline: 1.3360x; 1.3159x over previous
//
#include <hip/hip_runtime.h>
#include <stdint.h>

// ---- problem constants ----
#define DIM    512
#define DSTATE 16
#define DINNER 1024
#define DTRANK 32
#define BB     2
#define LL     2048
#define NTOK   (BB*LL)      // 4096
#define NCHUNK 64
#define CLEN   (LL/NCHUNK)  // 32
#define NSUB   4
#define SLEN   (CLEN/NSUB)  // 8
#define CPB    64           // channels per scan block (256 thr = 64ch x 4 subs)
#define NP     8            // x_proj K-split partials

typedef __bf16 bf16;
typedef bf16  bf16x8 __attribute__((ext_vector_type(8)));
typedef bf16  bf16x2 __attribute__((ext_vector_type(2)));
typedef float f32x4  __attribute__((ext_vector_type(4)));

// I/O dtype: FP32. Internals: bf16.
// Perf ledger: r11=222.1, r14=219.1, r16(delta fused into scan_a)=197.3 BEST,
// r17(conv->x_proj)=258.4 FAILED, r18(NCHUNK=128)=197.6 NEUTRAL,
// r19(cooperative)=WRONG, r20/r21(sub-split @1024thr)=272/268 FAILED:
// 1024-thr blocks are hard-capped at 64 VGPR on gfx950 (launch_bounds(1024,4)
// did NOT lift it; VGPR_Count=64 both rounds) -> ~110-reg scan state spilled
// (~360MB scratch traffic/dispatch). Sub-split MATH verified correct twice.
// This round: sub-split via 256-thr blocks (64 channels x 4 subs, sub=wave,
// wave-uniform), grid (16,NCHUNK,BB)=2048 blocks. ~110 VGPR -> 16 waves/CU
// by VGPR rule, no spill. Cost: 4x redundant xdbl panel staging (~+75MB of
// L2 reads, ~+2-3us) vs halving the serial chain + killing spill.

static __device__ __forceinline__ bf16x8 cvt8(const float* p)
{
    f32x4 a = *(const f32x4*)p, b = *(const f32x4*)(p + 4);
    bf16x8 o;
#pragma unroll
    for (int i = 0; i < 4; i++) { o[i] = (bf16)a[i]; o[4 + i] = (bf16)b[i]; }
    return o;
}

// async global->LDS, 16B per lane; LDS dest = wave-uniform base + lane*16 [m97]
static __device__ __forceinline__ void gload_lds16(const bf16* g, bf16* l)
{
    __builtin_amdgcn_global_load_lds(
        (const __attribute__((address_space(1))) void*)g,
        (__attribute__((address_space(3))) void*)l, 16, 0, 0);
}

// ---- bf16 weight shadow ----
#define WIN_N  (2*DINNER*DIM)          // 1,048,576
#define WX_N   (64*DINNER)             // 65,536
#define WOUT_N (DIM*DINNER)            // 524,288
#define WCVT_BLOCKS 800                // (WIN_N+WX_N+WOUT_N)/(256*8)
#define LN_BLOCKS   (NTOK/4)           // 1024

// ---------------------------------------------------------------------------
// prep: [0,800) weight cvt | [800,1824) LayerNorm
// ---------------------------------------------------------------------------
__global__ __launch_bounds__(256) void prep_kernel(const float* __restrict__ win,
                                                   const float* __restrict__ wx,
                                                   const float* __restrict__ wout,
                                                   bf16* __restrict__ wb,
                                                   const float* __restrict__ x,
                                                   const float* __restrict__ gamma,
                                                   const float* __restrict__ beta,
                                                   bf16* __restrict__ h)
{
    if (blockIdx.x < WCVT_BLOCKS) {
        int i = (blockIdx.x * 256 + threadIdx.x) * 8;
        const float* s; int j; bf16* dpt;
        if      (i < WIN_N)        { s = win;  j = i;                 dpt = wb; }
        else if (i < WIN_N + WX_N) { s = wx;   j = i - WIN_N;         dpt = wb + WIN_N; }
        else                       { s = wout; j = i - WIN_N - WX_N;  dpt = wb + WIN_N + WX_N; }
        *(bf16x8*)&dpt[j] = cvt8(&s[j]);
        return;
    }
    int bid = blockIdx.x - WCVT_BLOCKS;
    int w = threadIdx.x >> 6, lane = threadIdx.x & 63;
    int token = bid * 4 + w;
    const float* xr = x + (size_t)token * DIM + lane * 8;
    f32x4 va = *(const f32x4*)xr, vb = *(const f32x4*)(xr + 4);
    float vals[8];
#pragma unroll
    for (int i = 0; i < 4; i++) { vals[i] = va[i]; vals[4 + i] = vb[i]; }
    float s = 0.f;
#pragma unroll
    for (int i = 0; i < 8; i++) s += vals[i];
#pragma unroll
    for (int off = 32; off > 0; off >>= 1) s += __shfl_xor(s, off);
    float mean = s * (1.f / DIM);
    float vs = 0.f;
#pragma unroll
    for (int i = 0; i < 8; i++) { float d = vals[i] - mean; vs += d * d; }
#pragma unroll
    for (int off = 32; off > 0; off >>= 1) vs += __shfl_xor(vs, off);
    float rstd = rsqrtf(vs * (1.f / DIM) + 1e-5f);
    f32x4 ga = *(const f32x4*)(gamma + lane * 8), gb = *(const f32x4*)(gamma + lane * 8 + 4);
    f32x4 ba = *(const f32x4*)(beta + lane * 8),  bb = *(const f32x4*)(beta + lane * 8 + 4);
    bf16x8 o;
#pragma unroll
    for (int i = 0; i < 4; i++) {
        o[i]     = (bf16)((vals[i]     - mean) * rstd * ga[i] + ba[i]);
        o[4 + i] = (bf16)((vals[4 + i] - mean) * rstd * gb[i] + bb[i]);
    }
    *(bf16x8*)(h + (size_t)token * DIM + lane * 8) = o;
}

// ---------------------------------------------------------------------------
// Tiled MFMA GEMM, single-buffer 2-barrier global_load_lds staging (r11 proven).
// C[M,N] = A[M,K(lda)] * W[N,K(ldb)]^T.
// EPI: 0 = store bf16, 1 = fp32 partial store Cout[z][M][N], 2 = fp32 resid+store
// ---------------------------------------------------------------------------
template<int BM, int BN, int TM, int TN, int EPI>
__global__ __launch_bounds__(256) void gemm_kernel(const bf16* __restrict__ A, int lda,
                                                   const bf16* __restrict__ Bw, int ldb,
                                                   void* __restrict__ Cout,
                                                   const float* __restrict__ resid,
                                                   int M, int N, int K,
                                                   int kStart, int kLen)
{
    constexpr int WCols = BN / (TN * 16);
    constexpr int WRows = 4 / WCols;
    static_assert(WRows * TM * 16 == BM, "tile mismatch");
    __shared__ __align__(16) bf16 lsA[BM * 32];
    __shared__ __align__(16) bf16 lsB[BN * 32];
    const int tid  = threadIdx.x;
    const int lane = tid & 63;
    const int w    = tid >> 6;
    const int wr = w / WCols, wc = w % WCols;
    const int fr = lane & 15, q = lane >> 4;
    const int m0 = blockIdx.y * BM, n0 = blockIdx.x * BN;
    const int ks = kStart + blockIdx.z * kLen;

    f32x4 acc[TM][TN];
#pragma unroll
    for (int i = 0; i < TM; i++)
#pragma unroll
        for (int j = 0; j < TN; j++) acc[i][j] = (f32x4){0.f, 0.f, 0.f, 0.f};

    constexpr int NCA = (BM * 4) / 256;
    constexpr int NCB = (BN * 4) / 256;

    for (int k0 = ks; k0 < ks + kLen; k0 += 32) {
        __syncthreads();
#pragma unroll
        for (int c = 0; c < NCA; c++) {
            int lin = tid + c * 256;
            gload_lds16(&A[(size_t)(m0 + (lin >> 2)) * lda + k0 + (lin & 3) * 8], &lsA[lin * 8]);
        }
#pragma unroll
        for (int c = 0; c < NCB; c++) {
            int lin = tid + c * 256;
            gload_lds16(&Bw[(size_t)(n0 + (lin >> 2)) * ldb + k0 + (lin & 3) * 8], &lsB[lin * 8]);
        }
        __syncthreads();
        bf16x8 af[TM], bfr[TN];
#pragma unroll
        for (int i = 0; i < TM; i++)
            af[i] = *(const bf16x8*)&lsA[(wr * TM * 16 + i * 16 + fr) * 32 + q * 8];
#pragma unroll
        for (int j = 0; j < TN; j++)
            bfr[j] = *(const bf16x8*)&lsB[(wc * TN * 16 + j * 16 + fr) * 32 + q * 8];
#pragma unroll
        for (int i = 0; i < TM; i++)
#pragma unroll
            for (int j = 0; j < TN; j++)
                acc[i][j] = __builtin_amdgcn_mfma_f32_16x16x32_bf16(af[i], bfr[j], acc[i][j], 0, 0, 0);
    }

    // epilogue: D[m][n] -> col = lane&15, row = (lane>>4)*4 + r  [m89/m91]
#pragma unroll
    for (int i = 0; i < TM; i++) {
#pragma unroll
        for (int j = 0; j < TN; j++) {
#pragma unroll
            for (int r = 0; r < 4; r++) {
                int row = m0 + wr * TM * 16 + i * 16 + q * 4 + r;
                int col = n0 + wc * TN * 16 + j * 16 + fr;
                float v = acc[i][j][r];
                if (EPI == 0) {
                    ((bf16*)Cout)[(size_t)row * N + col] = (bf16)v;
                } else if (EPI == 1) {
                    ((float*)Cout)[((size_t)blockIdx.z * M + row) * N + col] = v;
                } else {
                    size_t idx = (size_t)row * N + col;
                    ((float*)Cout)[idx] = resid[idx] + v;
                }
            }
        }
    }
}

// ---------------------------------------------------------------------------
// Depthwise causal conv (taps=4) + bias + SiLU. 8 channels/thread, bf16x8 I/O.
// ---------------------------------------------------------------------------
__global__ __launch_bounds__(256) void conv_kernel(const bf16* __restrict__ xz,
                                                   const float* __restrict__ cw,
                                                   const float* __restrict__ cb,
                                                   bf16* __restrict__ uact)
{
    int idx = blockIdx.x * 256 + threadIdx.x;   // NTOK * 128
    int c   = (idx & 127) * 8;
    int tok = idx >> 7;
    int b = tok >> 11, l = tok & 2047;
    float a[8];
    {
        f32x4 c0 = *(const f32x4*)&cb[c], c1 = *(const f32x4*)&cb[c + 4];
#pragma unroll
        for (int j = 0; j < 4; j++) { a[j] = c0[j]; a[4 + j] = c1[j]; }
    }
    float wv[8][4];
#pragma unroll
    for (int j = 0; j < 8; j++) {
        f32x4 wq = *(const f32x4*)&cw[(c + j) * 4];
#pragma unroll
        for (int k = 0; k < 4; k++) wv[j][k] = wq[k];
    }
#pragma unroll
    for (int k = 0; k < 4; k++) {
        int ls = l - 3 + k;
        if (ls >= 0) {
            bf16x8 uv = *(const bf16x8*)&xz[((size_t)(b * LL + ls)) * (2 * DINNER) + c];
#pragma unroll
            for (int j = 0; j < 8; j++) a[j] += (float)uv[j] * wv[j][k];
        }
    }
    bf16x8 o;
#pragma unroll
    for (int j = 0; j < 8; j++) {
        float v = a[j] / (1.f + __expf(-a[j]));
        o[j] = (bf16)v;
    }
    *(bf16x8*)&uact[(size_t)tok * DINNER + c] = o;
}

static __device__ __forceinline__ float softplusf(float v)
{
    return (v > 20.f) ? v : __logf(1.f + __expf(v));
}

// ---------------------------------------------------------------------------
// scan_a, sub-chunk split @256thr: 64 channels x NSUB subs (sub = wave idx).
// Each thread scans SLEN=8 tokens; LDS combine (P=exp(An*sd_sub)) builds the
// chunk-level S/sumd with semantics identical to the serial 32-token scan.
// ---------------------------------------------------------------------------
__global__ __launch_bounds__(256) void scan_a(const bf16* __restrict__ uact,
                                              const float* __restrict__ xdblp,
                                              const float* __restrict__ wdt,
                                              const float* __restrict__ bdt,
                                              const float* __restrict__ Alog,
                                              float* __restrict__ S,
                                              float* __restrict__ sumd,
                                              bf16* __restrict__ delta)
{
    const int tid  = threadIdx.x;
    const int sub  = tid >> 6, dloc = tid & 63;   // sub is wave-uniform
    const int d    = blockIdx.x * CPB + dloc;
    const int chunk = blockIdx.y, b = blockIdx.z;
    const int tok0 = b * LL + chunk * CLEN;
    const int ts0  = tok0 + sub * SLEN;

    __shared__ float sS[CLEN][48];          // x_dbl cols [0,48) NP-summed
    __shared__ float hcomb[NSUB][CPB][17];  // stride 17: conflict-free
    __shared__ float sdl[NSUB][CPB];

    for (int t = tid; t < CLEN * 12; t += 256) {
        int l = t / 12, part = t % 12;
        f32x4 acc = (f32x4){0.f, 0.f, 0.f, 0.f};
#pragma unroll
        for (int p = 0; p < NP; p++)
            acc += *(const f32x4*)&xdblp[((size_t)p * NTOK + tok0 + l) * 64 + part * 4];
        *(f32x4*)&sS[l][part * 4] = acc;
    }

    // dt_proj row (fp32) — live only through the delta dot
    f32x4 wv[8];
#pragma unroll
    for (int i = 0; i < 8; i++) wv[i] = *(const f32x4*)&wdt[(size_t)d * 32 + i * 4];
    float bd = bdt[d];

    bf16 uu[SLEN];
#pragma unroll
    for (int l = 0; l < SLEN; l++)
        uu[l] = uact[(size_t)(ts0 + l) * DINNER + d];

    __syncthreads();

    bf16 dl[SLEN];
#pragma unroll
    for (int l = 0; l < SLEN; l++) {
        float acc = bd;
        const float* row = &sS[sub * SLEN + l][0];
#pragma unroll
        for (int r = 0; r < 8; r++) {
            f32x4 w4 = wv[r];
            acc += row[4 * r + 0] * w4[0] + row[4 * r + 1] * w4[1]
                 + row[4 * r + 2] * w4[2] + row[4 * r + 3] * w4[3];
        }
        bf16 dq = (bf16)softplusf(acc);
        dl[l] = dq;
        delta[(size_t)(ts0 + l) * DINNER + d] = dq;
    }

    float An[16];
#pragma unroll
    for (int n = 0; n < 16; n += 4) {
        f32x4 v = *(const f32x4*)&Alog[(size_t)d * 16 + n];
        An[n] = -__expf(v[0]); An[n + 1] = -__expf(v[1]);
        An[n + 2] = -__expf(v[2]); An[n + 3] = -__expf(v[3]);
    }

    // local sub-scan (zero entry)
    float h[16];
#pragma unroll
    for (int n = 0; n < 16; n++) h[n] = 0.f;
    float sd = 0.f;
#pragma unroll
    for (int l = 0; l < SLEN; l++) {
        float dc = (float)dl[l];
        float du = dc * (float)uu[l];
        sd += dc;
        const float* Brow = &sS[sub * SLEN + l][32];
#pragma unroll
        for (int n = 0; n < 16; n++) {
            float dA = __expf(dc * An[n]);
            h[n] = dA * h[n] + du * Brow[n];
        }
    }
#pragma unroll
    for (int n = 0; n < 16; n++) hcomb[sub][dloc][n] = h[n];
    sdl[sub][dloc] = sd;
    __syncthreads();

    if (sub == NSUB - 1) {
        // combine subs 0..2, then fold own (sub 3) state
        float e[16];
#pragma unroll
        for (int n = 0; n < 16; n++) e[n] = hcomb[0][dloc][n];
        float sdtot = sdl[0][dloc];
#pragma unroll
        for (int t = 1; t < NSUB - 1; t++) {
            float sdt = sdl[t][dloc];
            sdtot += sdt;
#pragma unroll
            for (int n = 0; n < 16; n++)
                e[n] = hcomb[t][dloc][n] + __expf(An[n] * sdt) * e[n];
        }
        sdtot += sd;
        float hc[16];
#pragma unroll
        for (int n = 0; n < 16; n++)
            hc[n] = h[n] + __expf(An[n] * sd) * e[n];

        size_t base = (((size_t)(b * NCHUNK + chunk)) << 14) + (size_t)d * 16;
#pragma unroll
        for (int n = 0; n < 16; n += 4)
            *(f32x4*)&S[base + n] = (f32x4){hc[n], hc[n + 1], hc[n + 2], hc[n + 3]};
        sumd[(b * NCHUNK + chunk) * DINNER + d] = sdtot;
    }
}

// Pass B: serial over chunks; P = exp(An * sumdelta). IN-PLACE entry states.
__global__ __launch_bounds__(256) void scan_b(float* __restrict__ S,
                                              const float* __restrict__ sumd,
                                              const float* __restrict__ Alog)
{
    int idx = blockIdx.x * 256 + threadIdx.x;   // BB * DINNER * DSTATE
    int b = idx >> 14, dn = idx & 16383;
    int d = dn >> 4;
    float An = -__expf(Alog[dn]);               // dn == d*16+n
    float hc = 0.f;
#pragma unroll
    for (int c = 0; c < NCHUNK; c++) {
        size_t o = (((size_t)(b * NCHUNK + c)) << 14) + dn;
        float s_loc = S[o];
        float P = __expf(An * sumd[(b * NCHUNK + c) * DINNER + d]);
        S[o] = hc;
        hc = P * hc + s_loc;
    }
}

// ---------------------------------------------------------------------------
// scan_c, sub-chunk split @256thr. Pass 1: local h + sd per sub; combine
// gives each sub its entry (Hent reloaded after pass 1, L2-hot); pass 2:
// rescan emitting y = C.h + u*D, gated silu(z).
// ---------------------------------------------------------------------------
__global__ __launch_bounds__(256) void scan_c(const bf16* __restrict__ delta,
                                              const bf16* __restrict__ uact,
                                              const float* __restrict__ xdblp,
                                              const float* __restrict__ Alog,
                                              const float* __restrict__ Hent,
                                              bf16* xz,
                                              const float* __restrict__ Dvec)
{
    const int tid  = threadIdx.x;
    const int sub  = tid >> 6, dloc = tid & 63;
    const int d    = blockIdx.x * CPB + dloc;
    const int chunk = blockIdx.y, b = blockIdx.z;
    const int tok0 = b * LL + chunk * CLEN;
    const int ts0  = tok0 + sub * SLEN;

    __shared__ float sBC[CLEN][32];         // x_dbl cols [32,64) NP-summed
    __shared__ float hcomb[NSUB][CPB][17];
    __shared__ float sdl[NSUB][CPB];

    if (tid < CLEN * 8) {
        int l = tid >> 3, part = tid & 7;
        f32x4 acc = (f32x4){0.f, 0.f, 0.f, 0.f};
#pragma unroll
        for (int p = 0; p < NP; p++)
            acc += *(const f32x4*)&xdblp[((size_t)p * NTOK + tok0 + l) * 64 + 32 + part * 4];
        *(f32x4*)&sBC[l][part * 4] = acc;
    }

    float An[16];
#pragma unroll
    for (int n = 0; n < 16; n += 4) {
        f32x4 v = *(const f32x4*)&Alog[(size_t)d * 16 + n];
        An[n] = -__expf(v[0]); An[n + 1] = -__expf(v[1]);
        An[n + 2] = -__expf(v[2]); An[n + 3] = -__expf(v[3]);
    }
    bf16 dl[SLEN], uu[SLEN], zz[SLEN];
#pragma unroll
    for (int l = 0; l < SLEN; l++) {
        dl[l] = delta[(size_t)(ts0 + l) * DINNER + d];
        uu[l] = uact [(size_t)(ts0 + l) * DINNER + d];
        zz[l] = xz[(size_t)(ts0 + l) * (2 * DINNER) + DINNER + d];
    }
    float Dv = Dvec[d];
    __syncthreads();

    // pass 1: local h (zero entry) + sd
    {
        float h[16];
#pragma unroll
        for (int n = 0; n < 16; n++) h[n] = 0.f;
        float sd = 0.f;
#pragma unroll
        for (int l = 0; l < SLEN; l++) {
            float dc = (float)dl[l];
            float du = dc * (float)uu[l];
            sd += dc;
            const float* Brow = &sBC[sub * SLEN + l][0];
#pragma unroll
            for (int n = 0; n < 16; n++) {
                float dA = __expf(dc * An[n]);
                h[n] = dA * h[n] + du * Brow[n];
            }
        }
#pragma unroll
        for (int n = 0; n < 16; n++) hcomb[sub][dloc][n] = h[n];
        sdl[sub][dloc] = sd;
    }
    __syncthreads();

    // entry for this sub: fold Hent (reloaded here, L2-hot) through prev subs
    float e[16];
    {
        size_t hbase = (((size_t)(b * NCHUNK + chunk)) << 14) + (size_t)d * 16;
#pragma unroll
        for (int n = 0; n < 16; n += 4) {
            f32x4 t = *(const f32x4*)&Hent[hbase + n];
            e[n] = t[0]; e[n + 1] = t[1]; e[n + 2] = t[2]; e[n + 3] = t[3];
        }
    }
    for (int t = 0; t < sub; t++) {
        float sdt = sdl[t][dloc];
#pragma unroll
        for (int n = 0; n < 16; n++)
            e[n] = hcomb[t][dloc][n] + __expf(An[n] * sdt) * e[n];
    }

    // pass 2: rescan emitting y
#pragma unroll
    for (int l = 0; l < SLEN; l++) {
        float dc = (float)dl[l];
        float u  = (float)uu[l];
        float z  = (float)zz[l];
        float du = dc * u;
        float y = 0.f;
        const float* row = &sBC[sub * SLEN + l][0];
#pragma unroll
        for (int n = 0; n < 16; n++) {
            float dA = __expf(dc * An[n]);
            e[n] = dA * e[n] + du * row[n];
            y += e[n] * row[16 + n];
        }
        float sz = z / (1.f + __expf(-z));
        xz[(size_t)(ts0 + l) * (2 * DINNER) + d] = (bf16)((y + u * Dv) * sz);
    }
}

// ---------------------------------------------------------------------------
extern "C" void kernel_launch(void* const* d_in, const int* in_sizes, int n_in,
                              void* d_out, int out_size, void* d_ws, size_t ws_size,
                              hipStream_t stream)
{
    const int sh = (n_in >= 13) ? 0 : -1;   // tolerate dropped bool mask
    const float* x     = (const float*)d_in[0];
    const float* gamma = (const float*)d_in[2 + sh];
    const float* beta  = (const float*)d_in[3 + sh];
    const float* win   = (const float*)d_in[4 + sh];
    const float* cw    = (const float*)d_in[5 + sh];
    const float* cb    = (const float*)d_in[6 + sh];
    const float* wx    = (const float*)d_in[7 + sh];
    const float* wdt   = (const float*)d_in[8 + sh];
    const float* bdt   = (const float*)d_in[9 + sh];
    const float* alog  = (const float*)d_in[10 + sh];
    const float* Dv    = (const float*)d_in[11 + sh];
    const float* wout  = (const float*)d_in[12 + sh];

    char* ws = (char*)d_ws;
    // Memory map (~51.2 MB of 256 MiB ws):
    //   [0,4)MB    : h (LN out) -> [0,8)MB delta after gemm_in (h dead)
    //   [8,24)MB   : xz ; yg written in-place into u-columns by scan_c
    //   [24,32)MB  : uact
    //   [32,40)MB  : xdblp fp32 partials [NP][NTOK][64]
    //   [40,48)MB  : S (entry states in-place after scan_b)
    //   [48,51.2)MB: bf16 weight shadow (win | wx | wout)
    //   sumdelta (512 KB fp32) lives in d_out (dead before out_proj).
    bf16*  h     = (bf16*)(ws);
    bf16*  delta = (bf16*)(ws);
    bf16*  xz    = (bf16*)(ws + (8u  << 20));
    bf16*  uact  = (bf16*)(ws + (24u << 20));
    float* xdblp = (float*)(ws + (32u << 20));
    float* S     = (float*)(ws + (40u << 20));
    bf16*  wb    = (bf16*)(ws + (48u << 20));
    float* sumd  = (float*)d_out;

    const bf16* win_b  = wb;
    const bf16* wx_b   = wb + WIN_N;
    const bf16* wout_b = wb + WIN_N + WX_N;

    // 1. weight cvt + LayerNorm
    prep_kernel<<<WCVT_BLOCKS + LN_BLOCKS, 256, 0, stream>>>(
        win, wx, wout, wb, x, gamma, beta, h);

    // 2. in_proj: [4096,512] x [2048,512]^T -> xz [4096,2048] bf16
    gemm_kernel<128, 128, 4, 4, 0><<<dim3(16, 32, 1), 256, 0, stream>>>(
        h, DIM, win_b, DIM, xz, nullptr, NTOK, 2 * DINNER, DIM, 0, DIM);

    // 3. conv + SiLU (2048 blocks, bf16x8)
    conv_kernel<<<(NTOK * (DINNER / 8)) / 256, 256, 0, stream>>>(xz, cw, cb, uact);

    // 4. x_proj: K-split 8, direct fp32 partial stores (512 blocks)
    gemm_kernel<64, 64, 2, 2, 1><<<dim3(1, 64, NP), 256, 0, stream>>>(
        uact, DINNER, wx_b, DINNER, xdblp, nullptr, NTOK, 64, DINNER, 0, DINNER / NP);

    // 5-7. chunked scan (sub-split @256thr, 2048 blocks; scan_b unchanged)
    scan_a<<<dim3(DINNER / CPB, NCHUNK, BB), 256, 0, stream>>>(uact, xdblp, wdt, bdt, alog, S, sumd, delta);
    scan_b<<<(BB * DINNER * DSTATE) / 256, 256, 0, stream>>>(S, sumd, alog);
    scan_c<<<dim3(DINNER / CPB, NCHUNK, BB), 256, 0, stream>>>(delta, uact, xdblp, alog, S, xz, Dv);

    // 8. out_proj + residual -> d_out fp32 (512 blocks, 2/CU)
    gemm_kernel<64, 64, 2, 2, 2><<<dim3(8, 64, 1), 256, 0, stream>>>(
        xz, 2 * DINNER, wout_b, DINNER, d_out, x, NTOK, DIM, DINNER, 0, DINNER);
}

// Round 9
// 196.157 us; speedup vs baseline: 1.3896x; 1.0401x over previous
//
#include <hip/hip_runtime.h>
#include <stdint.h>

// ---- problem constants ----
#define DIM    512
#define DSTATE 16
#define DINNER 1024
#define DTRANK 32
#define BB     2
#define LL     2048
#define NTOK   (BB*LL)      // 4096
#define NCHUNK 64
#define CLEN   (LL/NCHUNK)  // 32
#define NP     8            // x_proj K-split partials

typedef __bf16 bf16;
typedef bf16  bf16x8 __attribute__((ext_vector_type(8)));
typedef bf16  bf16x2 __attribute__((ext_vector_type(2)));
typedef float f32x4  __attribute__((ext_vector_type(4)));

// I/O dtype: FP32. Internals: bf16.
// Perf ledger: r11=222.1, r14=219.1, r16(delta fused into scan_a)=197.3 BEST,
// r17(conv->x_proj)=258.4 FAILED, r18(NCHUNK=128)=197.6 NEUTRAL,
// r19(cooperative)=WRONG, r20/r21(sub-split @1024thr)=272/268 FAILED (64-VGPR
// cap -> spill), r22(sub-split @256thr)=204.0 FAILED (no spill but 4x stage
// redundancy + VGPR 68 > 64 step; sub-split abandoned — 3 strikes).
// This round: EXACT r16 scan structure + one tiny xsum reduce kernel.
// Both scans were re-summing the NP=8 x_proj partials from L2/HBM on every
// block (scan_a ~25MB + scan_c ~17MB of stage reads, 8-load chain per
// element). xsum materializes the sum once (9MB, ~2.5us); scans stage with
// ONE load per element, same p=0..7 f32x4 order -> bitwise-identical output.

static __device__ __forceinline__ bf16x8 cvt8(const float* p)
{
    f32x4 a = *(const f32x4*)p, b = *(const f32x4*)(p + 4);
    bf16x8 o;
#pragma unroll
    for (int i = 0; i < 4; i++) { o[i] = (bf16)a[i]; o[4 + i] = (bf16)b[i]; }
    return o;
}

// async global->LDS, 16B per lane; LDS dest = wave-uniform base + lane*16 [m97]
static __device__ __forceinline__ void gload_lds16(const bf16* g, bf16* l)
{
    __builtin_amdgcn_global_load_lds(
        (const __attribute__((address_space(1))) void*)g,
        (__attribute__((address_space(3))) void*)l, 16, 0, 0);
}

// ---- bf16 weight shadow ----
#define WIN_N  (2*DINNER*DIM)          // 1,048,576
#define WX_N   (64*DINNER)             // 65,536
#define WOUT_N (DIM*DINNER)            // 524,288
#define WCVT_BLOCKS 800                // (WIN_N+WX_N+WOUT_N)/(256*8)
#define LN_BLOCKS   (NTOK/4)           // 1024

// ---------------------------------------------------------------------------
// prep: [0,800) weight cvt | [800,1824) LayerNorm
// ---------------------------------------------------------------------------
__global__ __launch_bounds__(256) void prep_kernel(const float* __restrict__ win,
                                                   const float* __restrict__ wx,
                                                   const float* __restrict__ wout,
                                                   bf16* __restrict__ wb,
                                                   const float* __restrict__ x,
                                                   const float* __restrict__ gamma,
                                                   const float* __restrict__ beta,
                                                   bf16* __restrict__ h)
{
    if (blockIdx.x < WCVT_BLOCKS) {
        int i = (blockIdx.x * 256 + threadIdx.x) * 8;
        const float* s; int j; bf16* dpt;
        if      (i < WIN_N)        { s = win;  j = i;                 dpt = wb; }
        else if (i < WIN_N + WX_N) { s = wx;   j = i - WIN_N;         dpt = wb + WIN_N; }
        else                       { s = wout; j = i - WIN_N - WX_N;  dpt = wb + WIN_N + WX_N; }
        *(bf16x8*)&dpt[j] = cvt8(&s[j]);
        return;
    }
    int bid = blockIdx.x - WCVT_BLOCKS;
    int w = threadIdx.x >> 6, lane = threadIdx.x & 63;
    int token = bid * 4 + w;
    const float* xr = x + (size_t)token * DIM + lane * 8;
    f32x4 va = *(const f32x4*)xr, vb = *(const f32x4*)(xr + 4);
    float vals[8];
#pragma unroll
    for (int i = 0; i < 4; i++) { vals[i] = va[i]; vals[4 + i] = vb[i]; }
    float s = 0.f;
#pragma unroll
    for (int i = 0; i < 8; i++) s += vals[i];
#pragma unroll
    for (int off = 32; off > 0; off >>= 1) s += __shfl_xor(s, off);
    float mean = s * (1.f / DIM);
    float vs = 0.f;
#pragma unroll
    for (int i = 0; i < 8; i++) { float d = vals[i] - mean; vs += d * d; }
#pragma unroll
    for (int off = 32; off > 0; off >>= 1) vs += __shfl_xor(vs, off);
    float rstd = rsqrtf(vs * (1.f / DIM) + 1e-5f);
    f32x4 ga = *(const f32x4*)(gamma + lane * 8), gb = *(const f32x4*)(gamma + lane * 8 + 4);
    f32x4 ba = *(const f32x4*)(beta + lane * 8),  bb = *(const f32x4*)(beta + lane * 8 + 4);
    bf16x8 o;
#pragma unroll
    for (int i = 0; i < 4; i++) {
        o[i]     = (bf16)((vals[i]     - mean) * rstd * ga[i] + ba[i]);
        o[4 + i] = (bf16)((vals[4 + i] - mean) * rstd * gb[i] + bb[i]);
    }
    *(bf16x8*)(h + (size_t)token * DIM + lane * 8) = o;
}

// ---------------------------------------------------------------------------
// Tiled MFMA GEMM, single-buffer 2-barrier global_load_lds staging (r11 proven).
// C[M,N] = A[M,K(lda)] * W[N,K(ldb)]^T.
// EPI: 0 = store bf16, 1 = fp32 partial store Cout[z][M][N], 2 = fp32 resid+store
// ---------------------------------------------------------------------------
template<int BM, int BN, int TM, int TN, int EPI>
__global__ __launch_bounds__(256) void gemm_kernel(const bf16* __restrict__ A, int lda,
                                                   const bf16* __restrict__ Bw, int ldb,
                                                   void* __restrict__ Cout,
                                                   const float* __restrict__ resid,
                                                   int M, int N, int K,
                                                   int kStart, int kLen)
{
    constexpr int WCols = BN / (TN * 16);
    constexpr int WRows = 4 / WCols;
    static_assert(WRows * TM * 16 == BM, "tile mismatch");
    __shared__ __align__(16) bf16 lsA[BM * 32];
    __shared__ __align__(16) bf16 lsB[BN * 32];
    const int tid  = threadIdx.x;
    const int lane = tid & 63;
    const int w    = tid >> 6;
    const int wr = w / WCols, wc = w % WCols;
    const int fr = lane & 15, q = lane >> 4;
    const int m0 = blockIdx.y * BM, n0 = blockIdx.x * BN;
    const int ks = kStart + blockIdx.z * kLen;

    f32x4 acc[TM][TN];
#pragma unroll
    for (int i = 0; i < TM; i++)
#pragma unroll
        for (int j = 0; j < TN; j++) acc[i][j] = (f32x4){0.f, 0.f, 0.f, 0.f};

    constexpr int NCA = (BM * 4) / 256;
    constexpr int NCB = (BN * 4) / 256;

    for (int k0 = ks; k0 < ks + kLen; k0 += 32) {
        __syncthreads();
#pragma unroll
        for (int c = 0; c < NCA; c++) {
            int lin = tid + c * 256;
            gload_lds16(&A[(size_t)(m0 + (lin >> 2)) * lda + k0 + (lin & 3) * 8], &lsA[lin * 8]);
        }
#pragma unroll
        for (int c = 0; c < NCB; c++) {
            int lin = tid + c * 256;
            gload_lds16(&Bw[(size_t)(n0 + (lin >> 2)) * ldb + k0 + (lin & 3) * 8], &lsB[lin * 8]);
        }
        __syncthreads();
        bf16x8 af[TM], bfr[TN];
#pragma unroll
        for (int i = 0; i < TM; i++)
            af[i] = *(const bf16x8*)&lsA[(wr * TM * 16 + i * 16 + fr) * 32 + q * 8];
#pragma unroll
        for (int j = 0; j < TN; j++)
            bfr[j] = *(const bf16x8*)&lsB[(wc * TN * 16 + j * 16 + fr) * 32 + q * 8];
#pragma unroll
        for (int i = 0; i < TM; i++)
#pragma unroll
            for (int j = 0; j < TN; j++)
                acc[i][j] = __builtin_amdgcn_mfma_f32_16x16x32_bf16(af[i], bfr[j], acc[i][j], 0, 0, 0);
    }

    // epilogue: D[m][n] -> col = lane&15, row = (lane>>4)*4 + r  [m89/m91]
#pragma unroll
    for (int i = 0; i < TM; i++) {
#pragma unroll
        for (int j = 0; j < TN; j++) {
#pragma unroll
            for (int r = 0; r < 4; r++) {
                int row = m0 + wr * TM * 16 + i * 16 + q * 4 + r;
                int col = n0 + wc * TN * 16 + j * 16 + fr;
                float v = acc[i][j][r];
                if (EPI == 0) {
                    ((bf16*)Cout)[(size_t)row * N + col] = (bf16)v;
                } else if (EPI == 1) {
                    ((float*)Cout)[((size_t)blockIdx.z * M + row) * N + col] = v;
                } else {
                    size_t idx = (size_t)row * N + col;
                    ((float*)Cout)[idx] = resid[idx] + v;
                }
            }
        }
    }
}

// ---------------------------------------------------------------------------
// Depthwise causal conv (taps=4) + bias + SiLU. 8 channels/thread, bf16x8 I/O.
// ---------------------------------------------------------------------------
__global__ __launch_bounds__(256) void conv_kernel(const bf16* __restrict__ xz,
                                                   const float* __restrict__ cw,
                                                   const float* __restrict__ cb,
                                                   bf16* __restrict__ uact)
{
    int idx = blockIdx.x * 256 + threadIdx.x;   // NTOK * 128
    int c   = (idx & 127) * 8;
    int tok = idx >> 7;
    int b = tok >> 11, l = tok & 2047;
    float a[8];
    {
        f32x4 c0 = *(const f32x4*)&cb[c], c1 = *(const f32x4*)&cb[c + 4];
#pragma unroll
        for (int j = 0; j < 4; j++) { a[j] = c0[j]; a[4 + j] = c1[j]; }
    }
    float wv[8][4];
#pragma unroll
    for (int j = 0; j < 8; j++) {
        f32x4 wq = *(const f32x4*)&cw[(c + j) * 4];
#pragma unroll
        for (int k = 0; k < 4; k++) wv[j][k] = wq[k];
    }
#pragma unroll
    for (int k = 0; k < 4; k++) {
        int ls = l - 3 + k;
        if (ls >= 0) {
            bf16x8 uv = *(const bf16x8*)&xz[((size_t)(b * LL + ls)) * (2 * DINNER) + c];
#pragma unroll
            for (int j = 0; j < 8; j++) a[j] += (float)uv[j] * wv[j][k];
        }
    }
    bf16x8 o;
#pragma unroll
    for (int j = 0; j < 8; j++) {
        float v = a[j] / (1.f + __expf(-a[j]));
        o[j] = (bf16)v;
    }
    *(bf16x8*)&uact[(size_t)tok * DINNER + c] = o;
}

// ---------------------------------------------------------------------------
// xsum: sum the NP x_proj partials once. xdblp[NP][NTOK][64] -> xsum[NTOK][64]
// Same order (p=0..7, f32x4 adds) as the old in-scan stage_sum -> bitwise same.
// ---------------------------------------------------------------------------
__global__ __launch_bounds__(256) void xsum_kernel(const float* __restrict__ xdblp,
                                                   float* __restrict__ xsum)
{
    int i = (blockIdx.x * 256 + threadIdx.x) * 4;   // 65536 quads total
    f32x4 acc = (f32x4){0.f, 0.f, 0.f, 0.f};
#pragma unroll
    for (int p = 0; p < NP; p++)
        acc += *(const f32x4*)&xdblp[(size_t)p * (NTOK * 64) + i];
    *(f32x4*)&xsum[i] = acc;
}

static __device__ __forceinline__ float softplusf(float v)
{
    return (v > 20.f) ? v : __logf(1.f + __expf(v));
}

// ---------------------------------------------------------------------------
// Chunked selective scan, pass A (delta fused in-thread, r16 proven).
// Stage now reads the pre-summed xsum: ONE load per element.
// ---------------------------------------------------------------------------
__global__ __launch_bounds__(256) void scan_a(const bf16* __restrict__ uact,
                                              const float* __restrict__ xsum,
                                              const float* __restrict__ wdt,
                                              const float* __restrict__ bdt,
                                              const float* __restrict__ Alog,
                                              float* __restrict__ S,
                                              float* __restrict__ sumd,
                                              bf16* __restrict__ delta)
{
    const int d = blockIdx.x * 256 + threadIdx.x;
    const int chunk = blockIdx.y, b = blockIdx.z;
    const int tok0 = b * LL + chunk * CLEN;

    __shared__ float sS[CLEN][48];    // x_dbl cols [0,48) pre-summed
    for (int t = threadIdx.x; t < CLEN * 12; t += 256) {
        int l = t / 12, part = t % 12;
        *(f32x4*)&sS[l][part * 4] = *(const f32x4*)&xsum[(size_t)(tok0 + l) * 64 + part * 4];
    }

    // dt_proj row for this channel (fp32)
    f32x4 wv[8];
#pragma unroll
    for (int i = 0; i < 8; i++) wv[i] = *(const f32x4*)&wdt[(size_t)d * 32 + i * 4];
    float bd = bdt[d];

    bf16 uu[CLEN];
#pragma unroll
    for (int l = 0; l < CLEN; l++)
        uu[l] = uact[(size_t)(tok0 + l) * DINNER + d];

    __syncthreads();

    // delta: 32-long dot per token, softplus, bf16-quantize, store for scan_c
    bf16 dl[CLEN];
#pragma unroll
    for (int l = 0; l < CLEN; l++) {
        float acc = bd;
#pragma unroll
        for (int r = 0; r < 8; r++) {
            f32x4 w4 = wv[r];
            acc += sS[l][4 * r + 0] * w4[0] + sS[l][4 * r + 1] * w4[1]
                 + sS[l][4 * r + 2] * w4[2] + sS[l][4 * r + 3] * w4[3];
        }
        bf16 dq = (bf16)softplusf(acc);
        dl[l] = dq;
        delta[(size_t)(tok0 + l) * DINNER + d] = dq;
    }

    float An[16];
#pragma unroll
    for (int n = 0; n < 16; n += 4) {
        f32x4 v = *(const f32x4*)&Alog[(size_t)d * 16 + n];
        An[n] = -__expf(v[0]); An[n + 1] = -__expf(v[1]);
        An[n + 2] = -__expf(v[2]); An[n + 3] = -__expf(v[3]);
    }

    float h[16];
#pragma unroll
    for (int n = 0; n < 16; n++) h[n] = 0.f;
    float sd = 0.f;
#pragma unroll
    for (int l = 0; l < CLEN; l++) {
        float dc = (float)dl[l];
        float du = dc * (float)uu[l];
        sd += dc;
#pragma unroll
        for (int n = 0; n < 16; n++) {
            float dA = __expf(dc * An[n]);
            h[n] = dA * h[n] + du * sS[l][32 + n];
        }
    }
    size_t base = (((size_t)(b * NCHUNK + chunk)) << 14) + (size_t)d * 16;
#pragma unroll
    for (int n = 0; n < 16; n += 4)
        *(f32x4*)&S[base + n] = (f32x4){h[n], h[n + 1], h[n + 2], h[n + 3]};
    sumd[(b * NCHUNK + chunk) * DINNER + d] = sd;
}

// Pass B: serial over chunks; P = exp(An * sumdelta). IN-PLACE entry states.
__global__ __launch_bounds__(256) void scan_b(float* __restrict__ S,
                                              const float* __restrict__ sumd,
                                              const float* __restrict__ Alog)
{
    int idx = blockIdx.x * 256 + threadIdx.x;   // BB * DINNER * DSTATE
    int b = idx >> 14, dn = idx & 16383;
    int d = dn >> 4;
    float An = -__expf(Alog[dn]);               // dn == d*16+n
    float hc = 0.f;
#pragma unroll
    for (int c = 0; c < NCHUNK; c++) {
        size_t o = (((size_t)(b * NCHUNK + c)) << 14) + dn;
        float s_loc = S[o];
        float P = __expf(An * sumd[(b * NCHUNK + c) * DINNER + d]);
        S[o] = hc;
        hc = P * hc + s_loc;
    }
}

// Pass C: re-scan with entry state; y = C.h + u*D, gate silu(z).
// xz: z read from cols [1024,2048), yg written into dead u-cols [0,1024).
__global__ __launch_bounds__(256) void scan_c(const bf16* __restrict__ delta,
                                              const bf16* __restrict__ uact,
                                              const float* __restrict__ xsum,
                                              const float* __restrict__ Alog,
                                              const float* __restrict__ Hent,
                                              bf16* xz,
                                              const float* __restrict__ Dvec)
{
    const int d = blockIdx.x * 256 + threadIdx.x;
    const int chunk = blockIdx.y, b = blockIdx.z;
    const int tok0 = b * LL + chunk * CLEN;

    __shared__ float sBC[CLEN][32];   // x_dbl cols [32,64) pre-summed
    if (threadIdx.x < CLEN * 8) {
        int l = threadIdx.x >> 3, part = threadIdx.x & 7;
        *(f32x4*)&sBC[l][part * 4] = *(const f32x4*)&xsum[(size_t)(tok0 + l) * 64 + 32 + part * 4];
    }

    float An[16];
#pragma unroll
    for (int n = 0; n < 16; n += 4) {
        f32x4 v = *(const f32x4*)&Alog[(size_t)d * 16 + n];
        An[n] = -__expf(v[0]); An[n + 1] = -__expf(v[1]);
        An[n + 2] = -__expf(v[2]); An[n + 3] = -__expf(v[3]);
    }
    bf16 dl[CLEN], uu[CLEN], zz[CLEN];
#pragma unroll
    for (int l = 0; l < CLEN; l++) {
        dl[l] = delta[(size_t)(tok0 + l) * DINNER + d];
        uu[l] = uact [(size_t)(tok0 + l) * DINNER + d];
        zz[l] = xz[(size_t)(tok0 + l) * (2 * DINNER) + DINNER + d];
    }
    float h[16];
    size_t hbase = (((size_t)(b * NCHUNK + chunk)) << 14) + (size_t)d * 16;
#pragma unroll
    for (int n = 0; n < 16; n += 4) {
        f32x4 t = *(const f32x4*)&Hent[hbase + n];
        h[n] = t[0]; h[n + 1] = t[1]; h[n + 2] = t[2]; h[n + 3] = t[3];
    }
    float Dv = Dvec[d];
    __syncthreads();

#pragma unroll
    for (int l = 0; l < CLEN; l++) {
        float dc = (float)dl[l];
        float u  = (float)uu[l];
        float z  = (float)zz[l];
        float du = dc * u;
        float y = 0.f;
#pragma unroll
        for (int n = 0; n < 16; n++) {
            float dA = __expf(dc * An[n]);
            h[n] = dA * h[n] + du * sBC[l][n];
            y += h[n] * sBC[l][16 + n];
        }
        float sz = z / (1.f + __expf(-z));
        xz[(size_t)(tok0 + l) * (2 * DINNER) + d] = (bf16)((y + u * Dv) * sz);
    }
}

// ---------------------------------------------------------------------------
extern "C" void kernel_launch(void* const* d_in, const int* in_sizes, int n_in,
                              void* d_out, int out_size, void* d_ws, size_t ws_size,
                              hipStream_t stream)
{
    const int sh = (n_in >= 13) ? 0 : -1;   // tolerate dropped bool mask
    const float* x     = (const float*)d_in[0];
    const float* gamma = (const float*)d_in[2 + sh];
    const float* beta  = (const float*)d_in[3 + sh];
    const float* win   = (const float*)d_in[4 + sh];
    const float* cw    = (const float*)d_in[5 + sh];
    const float* cb    = (const float*)d_in[6 + sh];
    const float* wx    = (const float*)d_in[7 + sh];
    const float* wdt   = (const float*)d_in[8 + sh];
    const float* bdt   = (const float*)d_in[9 + sh];
    const float* alog  = (const float*)d_in[10 + sh];
    const float* Dv    = (const float*)d_in[11 + sh];
    const float* wout  = (const float*)d_in[12 + sh];

    char* ws = (char*)d_ws;
    // Memory map (~53.2 MB of 256 MiB ws):
    //   [0,4)MB    : h (LN out) -> [0,8)MB delta after gemm_in (h dead)
    //   [8,24)MB   : xz ; yg written in-place into u-columns by scan_c
    //   [24,32)MB  : uact
    //   [32,40)MB  : xdblp fp32 partials [NP][NTOK][64]
    //   [40,48)MB  : S (entry states in-place after scan_b)
    //   [48,51.2)MB: bf16 weight shadow (win | wx | wout)
    //   [52,53)MB  : xsum fp32 [NTOK][64]
    //   sumdelta (512 KB fp32) lives in d_out (dead before out_proj).
    bf16*  h     = (bf16*)(ws);
    bf16*  delta = (bf16*)(ws);
    bf16*  xz    = (bf16*)(ws + (8u  << 20));
    bf16*  uact  = (bf16*)(ws + (24u << 20));
    float* xdblp = (float*)(ws + (32u << 20));
    float* S     = (float*)(ws + (40u << 20));
    bf16*  wb    = (bf16*)(ws + (48u << 20));
    float* xsum  = (float*)(ws + (52u << 20));
    float* sumd  = (float*)d_out;

    const bf16* win_b  = wb;
    const bf16* wx_b   = wb + WIN_N;
    const bf16* wout_b = wb + WIN_N + WX_N;

    // 1. weight cvt + LayerNorm
    prep_kernel<<<WCVT_BLOCKS + LN_BLOCKS, 256, 0, stream>>>(
        win, wx, wout, wb, x, gamma, beta, h);

    // 2. in_proj: [4096,512] x [2048,512]^T -> xz [4096,2048] bf16
    gemm_kernel<128, 128, 4, 4, 0><<<dim3(16, 32, 1), 256, 0, stream>>>(
        h, DIM, win_b, DIM, xz, nullptr, NTOK, 2 * DINNER, DIM, 0, DIM);

    // 3. conv + SiLU (2048 blocks, bf16x8)
    conv_kernel<<<(NTOK * (DINNER / 8)) / 256, 256, 0, stream>>>(xz, cw, cb, uact);

    // 4. x_proj: K-split 8, direct fp32 partial stores (512 blocks)
    gemm_kernel<64, 64, 2, 2, 1><<<dim3(1, 64, NP), 256, 0, stream>>>(
        uact, DINNER, wx_b, DINNER, xdblp, nullptr, NTOK, 64, DINNER, 0, DINNER / NP);

    // 5. xsum: reduce the NP partials once (256 blocks)
    xsum_kernel<<<(NTOK * 64 / 4) / 256, 256, 0, stream>>>(xdblp, xsum);

    // 6-8. chunked scan (r16 structure; stages read xsum with 1 load/element)
    scan_a<<<dim3(4, NCHUNK, BB), 256, 0, stream>>>(uact, xsum, wdt, bdt, alog, S, sumd, delta);
    scan_b<<<(BB * DINNER * DSTATE) / 256, 256, 0, stream>>>(S, sumd, alog);
    scan_c<<<dim3(4, NCHUNK, BB), 256, 0, stream>>>(delta, uact, xsum, alog, S, xz, Dv);

    // 9. out_proj + residual -> d_out fp32 (512 blocks, 2/CU)
    gemm_kernel<64, 64, 2, 2, 2><<<dim3(8, 64, 1), 256, 0, stream>>>(
        xz, 2 * DINNER, wout_b, DINNER, d_out, x, NTOK, DIM, DINNER, 0, DINNER);
}